// Round 13
// baseline (254.841 us; speedup 1.0000x reference)
//
#include <hip/hip_runtime.h>
#include <cstdint>

typedef __attribute__((ext_vector_type(8))) short bf16x8;
typedef __attribute__((ext_vector_type(4))) float f32x4;
typedef __attribute__((ext_vector_type(16))) float f32x16;
typedef __attribute__((ext_vector_type(4))) unsigned int u32x4;

__device__ __forceinline__ short f2b(float f) {
  unsigned u = __builtin_bit_cast(unsigned, f);
  unsigned r = (u + 0x7fffu + ((u >> 16) & 1u)) >> 16;
  return (short)(unsigned short)r;
}
__device__ __forceinline__ float b2f(short s) {
  unsigned u = ((unsigned)(unsigned short)s) << 16;
  return __builtin_bit_cast(float, u);
}

__device__ __forceinline__ void gload16(void* lds_dst, const void* gsrc) {
  __builtin_amdgcn_global_load_lds(
      (const __attribute__((address_space(1))) void*)gsrc,
      (__attribute__((address_space(3))) void*)lds_dst, 16, 0, 0);
}

__device__ __forceinline__ unsigned cvtpk(float a, float b) {
  unsigned r;
  asm("v_cvt_pk_bf16_f32 %0, %1, %2" : "=v"(r) : "v"(a), "v"(b));
  return r;
}
__device__ __forceinline__ unsigned shflx32(unsigned v) {
  return (unsigned)__shfl_xor((int)v, 32);
}
__device__ __forceinline__ float exp2x(float x) {
  float r;
  asm("v_exp_f32 %0, %1" : "=v"(r) : "v"(x));
  return r;
}

// cross-half swap
__device__ __forceinline__ void plswap(unsigned &a, unsigned &b) {
#if __has_builtin(__builtin_amdgcn_permlane32_swap)
  auto r = __builtin_amdgcn_permlane32_swap((int)a, (int)b, false, false);
  a = (unsigned)r[0];
  b = (unsigned)r[1];
#else
  const bool lo = ((threadIdx.x & 63) < 32);
  unsigned ax = shflx32(a), bx = shflx32(b);
  unsigned na = lo ? a : bx;
  unsigned nb = lo ? ax : b;
  a = na; b = nb;
#endif
}

// ---------------- fused prep: qkv_pack + Wp/W1/W2 transpose + LN1 ----------------
__global__ __launch_bounds__(256)
void prep_all(const float* __restrict__ Wq, const float* __restrict__ Wk,
              const float* __restrict__ Wv, const float* __restrict__ Wp,
              const float* __restrict__ W1, const float* __restrict__ W2,
              const float* __restrict__ x, const float* __restrict__ g1,
              const float* __restrict__ be1,
              short* __restrict__ WqkvT, short* __restrict__ WpT,
              short* __restrict__ W1T, short* __restrict__ W2T,
              short* __restrict__ hbuf)
{
  const int id = blockIdx.x;
  if (id < 12288) {
    __shared__ float tl[32][33];
    const int tx = threadIdx.x & 31;
    const int ty = threadIdx.x >> 5;
    if (id < 3072) {
      const int which = id >> 10;
      const int rem = id & 1023;
      const int head = rem >> 6;
      const int tile = rem & 63;
      const int tc = tile >> 1, td = tile & 1;
      const float* src = (which == 0 ? Wq : which == 1 ? Wk : Wv) + (long)head * 65536;
#pragma unroll
      for (int i2 = 0; i2 < 4; ++i2) {
        int i = ty + i2 * 8;
        tl[i][tx] = src[(long)(tc * 32 + i) * 64 + td * 32 + tx];
      }
      __syncthreads();
      const long base = (long)which * 1024 + head * 64 + td * 32;
#pragma unroll
      for (int i2 = 0; i2 < 4; ++i2) {
        int i = ty + i2 * 8;
        WqkvT[(base + i) * 1024 + tc * 32 + tx] = f2b(tl[tx][i]);
      }
    } else {
      const float* src;
      short* dst;
      int rows, cols, bx, by;
      if (id < 4096) {
        src = Wp; dst = WpT; rows = 1024; cols = 1024;
        const int k = id - 3072; bx = k & 31; by = k >> 5;
      } else if (id < 8192) {
        src = W1; dst = W1T; rows = 1024; cols = 4096;
        const int k = id - 4096; bx = k & 127; by = k >> 7;
      } else {
        src = W2; dst = W2T; rows = 4096; cols = 1024;
        const int k = id - 8192; bx = k & 31; by = k >> 5;
      }
#pragma unroll
      for (int i2 = 0; i2 < 4; ++i2) {
        int i = ty + i2 * 8;
        tl[i][tx] = src[(long)(by * 32 + i) * cols + bx * 32 + tx];
      }
      __syncthreads();
#pragma unroll
      for (int i2 = 0; i2 < 4; ++i2) {
        int i = ty + i2 * 8;
        dst[(long)(bx * 32 + i) * rows + by * 32 + tx] = f2b(tl[tx][i]);
      }
    }
  } else {
    const int row = id - 12288;
    const int t = threadIdx.x;
    const float4 v = ((const float4*)(x + (long)row * 1024))[t];
    float s = v.x + v.y + v.z + v.w;
    float ss = v.x * v.x + v.y * v.y + v.z * v.z + v.w * v.w;
#pragma unroll
    for (int off = 1; off < 64; off <<= 1) {
      s += __shfl_xor(s, off);
      ss += __shfl_xor(ss, off);
    }
    __shared__ float red[8];
    const int wave = t >> 6, lane = t & 63;
    if (lane == 0) { red[wave] = s; red[4 + wave] = ss; }
    __syncthreads();
    s = red[0] + red[1] + red[2] + red[3];
    ss = red[4] + red[5] + red[6] + red[7];
    const float mu = s * (1.f / 1024.f);
    const float rstd = rsqrtf(ss * (1.f / 1024.f) - mu * mu + 1e-5f);
    const float4 gv = ((const float4*)g1)[t];
    const float4 bv = ((const float4*)be1)[t];
    short4 ov;
    ov.x = f2b((v.x - mu) * rstd * gv.x + bv.x);
    ov.y = f2b((v.y - mu) * rstd * gv.y + bv.y);
    ov.z = f2b((v.z - mu) * rstd * gv.z + bv.z);
    ov.w = f2b((v.w - mu) * rstd * gv.w + bv.w);
    *(short4*)(hbuf + (long)row * 1024 + t * 4) = ov;
  }
}

// V part of qkv [4096][3072] -> Vt [16][64][4096] bf16
__global__ void vtrans(const short* __restrict__ qkv, short* __restrict__ Vt)
{
  __shared__ short tl[32][33];
  const int t0 = blockIdx.x * 32;
  const int c0 = blockIdx.y * 32;
  const int head = c0 >> 6, d0 = c0 & 63;
  const int tx = threadIdx.x;
#pragma unroll
  for (int i2 = 0; i2 < 4; ++i2) {
    int i = threadIdx.y + i2 * 8;
    tl[i][tx] = qkv[(long)(t0 + i) * 3072 + 2048 + c0 + tx];
  }
  __syncthreads();
#pragma unroll
  for (int i2 = 0; i2 < 4; ++i2) {
    int i = threadIdx.y + i2 * 8;
    Vt[(long)head * 262144 + (long)(d0 + i) * 4096 + t0 + tx] = tl[tx][i];
  }
}

// ---------------- layernorm (LN2) ----------------
__global__ __launch_bounds__(256)
void layernorm_bf16(const float* __restrict__ x, const float* __restrict__ g,
                    const float* __restrict__ be, short* __restrict__ outp)
{
  const int row = blockIdx.x;
  const int t = threadIdx.x;
  const float4 v = ((const float4*)(x + (long)row * 1024))[t];
  float s = v.x + v.y + v.z + v.w;
  float ss = v.x * v.x + v.y * v.y + v.z * v.z + v.w * v.w;
#pragma unroll
  for (int off = 1; off < 64; off <<= 1) {
    s += __shfl_xor(s, off);
    ss += __shfl_xor(ss, off);
  }
  __shared__ float red[8];
  const int wave = t >> 6, lane = t & 63;
  if (lane == 0) { red[wave] = s; red[4 + wave] = ss; }
  __syncthreads();
  s = red[0] + red[1] + red[2] + red[3];
  ss = red[4] + red[5] + red[6] + red[7];
  const float mu = s * (1.f / 1024.f);
  const float rstd = rsqrtf(ss * (1.f / 1024.f) - mu * mu + 1e-5f);
  const float4 gv = ((const float4*)g)[t];
  const float4 bv = ((const float4*)be)[t];
  short4 ov;
  ov.x = f2b((v.x - mu) * rstd * gv.x + bv.x);
  ov.y = f2b((v.y - mu) * rstd * gv.y + bv.y);
  ov.z = f2b((v.z - mu) * rstd * gv.z + bv.z);
  ov.w = f2b((v.w - mu) * rstd * gv.w + bv.w);
  *(short4*)(outp + (long)row * 1024 + t * 4) = ov;
}

// ---------------- GEMM 128x128, 8-wave, counted-vmcnt pipeline ----------------
template<int EPI>
__global__ __launch_bounds__(512, 2)
void gemm128(const short* __restrict__ A, const short* __restrict__ Bt,
             int N, int K, int NT,
             short* __restrict__ Cb, float* __restrict__ Cf,
             const float* __restrict__ bias, const float* __restrict__ resid)
{
  __shared__ __align__(16) short As[2 * 8192];
  __shared__ __align__(16) short Bs[2 * 8192];
  const int tid = threadIdx.x;
  const int lane = tid & 63;
  const int wave = tid >> 6;
  const int wm = wave >> 2;
  const int wn = wave & 3;
  const int l15 = lane & 15, lg = lane >> 4;

  const int nwg = gridDim.x * gridDim.y;
  const int lin = blockIdx.y * gridDim.x + blockIdx.x;
  const int swz = (lin & 7) * (nwg >> 3) + (lin >> 3);
  const long m0 = (long)(swz / gridDim.x) * 128;
  const long n0 = (long)(swz % gridDim.x) * 128;

  const int rloc = lane >> 3;
  const int csrc = (lane & 7) ^ rloc;
  const short* Ag = A + (m0 + wave * 8 + rloc) * K + csrc * 8;
  const short* Bg = Bt + (n0 + wave * 8 + rloc) * K + csrc * 8;
  const int wbase = wave * 512;

  f32x4 acc[4][2] = {};

#define STAGE128(buf, kt)                                                     \
  do {                                                                        \
    gload16(As + (buf) * 8192 + wbase, Ag + (kt));                            \
    gload16(As + (buf) * 8192 + 4096 + wbase, Ag + (long)64 * K + (kt));      \
    gload16(Bs + (buf) * 8192 + wbase, Bg + (kt));                            \
    gload16(Bs + (buf) * 8192 + 4096 + wbase, Bg + (long)64 * K + (kt));      \
  } while (0)

  STAGE128(0, 0);
  STAGE128(1, 64);
  asm volatile("s_waitcnt vmcnt(4)" ::: "memory");
  __builtin_amdgcn_sched_barrier(0);
  __builtin_amdgcn_s_barrier();
  __builtin_amdgcn_sched_barrier(0);

  const int cA = l15 & 7;
  for (int t = 0; t < NT; ++t) {
    const char* Ab = (const char*)(As + (t & 1) * 8192);
    const char* Bb = (const char*)(Bs + (t & 1) * 8192);
#pragma unroll
    for (int kk = 0; kk < 2; ++kk) {
      bf16x8 af[4], bk[2];
#pragma unroll
      for (int mi = 0; mi < 4; ++mi)
        af[mi] = *(const bf16x8*)(Ab + (wm * 64 + mi * 16 + l15) * 128 + 16 * ((kk * 4 + lg) ^ cA));
#pragma unroll
      for (int ni = 0; ni < 2; ++ni)
        bk[ni] = *(const bf16x8*)(Bb + (wn * 32 + ni * 16 + l15) * 128 + 16 * ((kk * 4 + lg) ^ cA));
      __builtin_amdgcn_s_setprio(1);
#pragma unroll
      for (int mi = 0; mi < 4; ++mi)
#pragma unroll
        for (int ni = 0; ni < 2; ++ni)
          acc[mi][ni] = __builtin_amdgcn_mfma_f32_16x16x32_bf16(af[mi], bk[ni], acc[mi][ni], 0, 0, 0);
      __builtin_amdgcn_s_setprio(0);
    }
    if (t == NT - 1) break;
    __builtin_amdgcn_s_barrier();
    __builtin_amdgcn_sched_barrier(0);
    if (t + 2 < NT) {
      STAGE128(t & 1, (long)(t + 2) * 64);
      asm volatile("s_waitcnt vmcnt(4)" ::: "memory");
    } else {
      asm volatile("s_waitcnt vmcnt(0)" ::: "memory");
    }
    __builtin_amdgcn_sched_barrier(0);
    __builtin_amdgcn_s_barrier();
    __builtin_amdgcn_sched_barrier(0);
  }
#undef STAGE128

#pragma unroll
  for (int mi = 0; mi < 4; ++mi) {
#pragma unroll
    for (int ni = 0; ni < 2; ++ni) {
      const long col = n0 + wn * 32 + ni * 16 + l15;
#pragma unroll
      for (int r = 0; r < 4; ++r) {
        const long row = m0 + wm * 64 + mi * 16 + lg * 4 + r;
        const long idx = row * N + col;
        float v = acc[mi][ni][r];
        if (EPI == 0) {
          Cb[idx] = f2b(v);
        } else {
          Cf[idx] = v + bias[col] + resid[idx];
        }
      }
    }
  }
}

// ---------------- GEMM 256x256, 8-wave, phase-interleaved ----------------
__device__ __forceinline__ void stage256(short* AsB, short* BsB,
                                         const short* Ag, const short* Bg,
                                         long kt, int K, int ldsoff)
{
#pragma unroll
  for (int p = 0; p < 4; ++p)
    gload16(AsB + p * 4096 + ldsoff, Ag + (long)p * 64 * K + kt);
#pragma unroll
  for (int p = 0; p < 4; ++p)
    gload16(BsB + p * 4096 + ldsoff, Bg + (long)p * 64 * K + kt);
}

template<int EPI>
__global__ __launch_bounds__(512, 2)
void gemm256(const short* __restrict__ A, const short* __restrict__ Bt,
             int N, int K, int NT,
             short* __restrict__ Cb, const float* __restrict__ bias)
{
  __shared__ __align__(16) short As[2 * 16384];
  __shared__ __align__(16) short Bs[2 * 16384];
  const int tid = threadIdx.x;
  const int lane = tid & 63;
  const int wave = tid >> 6;
  const int wm = wave >> 2;
  const int wn = wave & 3;
  const int l15 = lane & 15, lg = lane >> 4;

  const int nwg = gridDim.x * gridDim.y;
  const int lin = blockIdx.y * gridDim.x + blockIdx.x;
  const int swz = (lin & 7) * (nwg >> 3) + (lin >> 3);
  const long m0 = (long)(swz / gridDim.x) * 256;
  const long n0 = (long)(swz % gridDim.x) * 256;

  const int trow = tid >> 3;
  const int csrc = (tid & 7) ^ (trow & 7);
  const short* Ag = A + (m0 + trow) * K + csrc * 8;
  const short* Bg = Bt + (n0 + trow) * K + csrc * 8;
  const int ldsoff = wave * 512;

  f32x4 acc[8][4] = {};

  stage256(As, Bs, Ag, Bg, 0, K, ldsoff);
  asm volatile("s_waitcnt vmcnt(0)" ::: "memory");
  __builtin_amdgcn_sched_barrier(0);
  __builtin_amdgcn_s_barrier();
  __builtin_amdgcn_sched_barrier(0);

  const int cA = l15 & 7;
  for (int t = 0; t < NT; ++t) {
    const char* Ab = (const char*)(As + (t & 1) * 16384);
    const char* Bb = (const char*)(Bs + (t & 1) * 16384);
    short* Asn = As + ((t + 1) & 1) * 16384;
    short* Bsn = Bs + ((t + 1) & 1) * 16384;
    const bool more = (t + 1 < NT);
    const long ktn = (long)(t + 1) * 64;
    bf16x8 bk[4];
#pragma unroll
    for (int ph = 0; ph < 4; ++ph) {
      const int kk = ph >> 1;
      const int mh = (ph & 1) * 4;
      bf16x8 af[4];
#pragma unroll
      for (int mi = 0; mi < 4; ++mi)
        af[mi] = *(const bf16x8*)(Ab + (wm * 128 + (mh + mi) * 16 + l15) * 128 + 16 * ((kk * 4 + lg) ^ cA));
      if ((ph & 1) == 0) {
#pragma unroll
        for (int ni = 0; ni < 4; ++ni)
          bk[ni] = *(const bf16x8*)(Bb + (wn * 64 + ni * 16 + l15) * 128 + 16 * ((kk * 4 + lg) ^ cA));
      }
      if (more && ph == 0) {
#pragma unroll
        for (int p = 0; p < 4; ++p)
          gload16(Asn + p * 4096 + ldsoff, Ag + (long)p * 64 * K + ktn);
      }
      if (more && ph == 1) {
#pragma unroll
        for (int p = 0; p < 4; ++p)
          gload16(Bsn + p * 4096 + ldsoff, Bg + (long)p * 64 * K + ktn);
      }
      __builtin_amdgcn_s_barrier();
      asm volatile("s_waitcnt lgkmcnt(0)" ::: "memory");
      __builtin_amdgcn_sched_barrier(0);
      __builtin_amdgcn_s_setprio(1);
#pragma unroll
      for (int mi = 0; mi < 4; ++mi)
#pragma unroll
        for (int ni = 0; ni < 4; ++ni)
          acc[mh + mi][ni] = __builtin_amdgcn_mfma_f32_16x16x32_bf16(af[mi], bk[ni], acc[mh + mi][ni], 0, 0, 0);
      __builtin_amdgcn_s_setprio(0);
      if (ph == 3 && more) {
        asm volatile("s_waitcnt vmcnt(0)" ::: "memory");
        __builtin_amdgcn_sched_barrier(0);
      }
      __builtin_amdgcn_s_barrier();
      __builtin_amdgcn_sched_barrier(0);
    }
  }

#pragma unroll
  for (int mi = 0; mi < 8; ++mi) {
#pragma unroll
    for (int ni = 0; ni < 4; ++ni) {
      const long col = n0 + wn * 64 + ni * 16 + l15;
      const float bb = (EPI == 2) ? bias[col] : 0.f;
#pragma unroll
      for (int r = 0; r < 4; ++r) {
        const long row = m0 + wm * 128 + mi * 16 + lg * 4 + r;
        float v = acc[mi][ni][r];
        if (EPI == 2) { v += bb; v = v > 0.f ? v : 0.f; }
        Cb[row * N + col] = f2b(v);
      }
    }
  }
}

// ---------------- flash attention v7: cross-block kv-parity split ------------
// 2048 blocks = (head 16, qsuper 64, kv-parity 2), 4 waves (wq, ks) each.
// Zero-offset softmax makes partials ADDITIVE: each block computes partial
// unnormalized O (bf16) + partial l (fp32) over its kv-parity's tiles; a merge
// kernel computes (P0+P1)/(l0+l1). Single-slot wave-private K/V ring (v6 body).
// Block order: descending qsuper per XCD stream (LPT) + head-locality (2
// heads per XCD -> K/V L2-resident).
__device__ __forceinline__ void stage_k32(short* lds, const short* gRowBase)
{
  const int lane = threadIdx.x & 63;
  const int rloc = lane >> 3;
  const int cs = (lane & 7) ^ rloc;
#pragma unroll
  for (int p = 0; p < 4; ++p)
    gload16(lds + p * 512, gRowBase + (long)(p * 8 + rloc) * 3072 + cs * 8);
}
__device__ __forceinline__ void stage_v32(short* lds, const short* vHeadBase, int t0)
{
  const int lane = threadIdx.x & 63;
  const int rloc = lane >> 3;
  const int cs = (lane & 7) ^ rloc;
#pragma unroll
  for (int p = 0; p < 4; ++p) {
    const int row = p * 8 + rloc;
    const int d = row + ((cs & 4) << 3);
    gload16(lds + p * 512, vHeadBase + (long)d * 4096 + t0 + (cs & 3) * 8);
  }
}

__global__ __launch_bounds__(256)
void attn_fwd7(const short* __restrict__ qkv, const short* __restrict__ Vt,
               short* __restrict__ P0buf, short* __restrict__ P1buf,
               float* __restrict__ lbuf)   // [2][16][4096]
{
  __shared__ __align__(16) short POOL[4 * 4096];  // 32KB
  __shared__ float lAll[64];
  short* const OB = POOL;                         // aliased merge scratch

  const int tid = threadIdx.x;
  const int lane = tid & 63;
  const int wave = tid >> 6;      // 0..3
  const int wq = wave & 1;
  const int ks = wave >> 1;
  const int l31 = lane & 31;
  const int h = lane >> 5;
  const int rs = l31 & 7;

  // id decode: xcd-local stream of descending qsuper; 2 heads per XCD
  const int id = blockIdx.x;                 // 0..2047
  const int xcd = id & 7;
  const int k = id >> 3;                     // 0..255
  const int head = (xcd << 1) | (k & 1);
  const int qp = k >> 1;                     // 0..127
  const int qsuper = 63 - (qp >> 1);         // descending (LPT)
  const int parity = qp & 1;

  const short* Qg = qkv + head * 64;
  const short* Kg = qkv + 1024 + head * 64;
  const short* Vg = Vt + (long)head * 262144;
  short* Pout = parity ? P1buf : P0buf;

  short* Kw = POOL + wave * 4096;            // wave-private slot

  bf16x8 onesf;
#pragma unroll
  for (int j = 0; j < 8; ++j) onesf[j] = (short)0x3F80;

  const int q0 = qsuper * 64 + wq * 32;
  const int q = q0 + l31;
  const int nt = qsuper + 1;

  bf16x8 qf[4];
#pragma unroll
  for (int d = 0; d < 4; ++d) {
    bf16x8 tq = *(const bf16x8*)(Qg + (long)q * 3072 + d * 16 + h * 8);
#pragma unroll
    for (int j = 0; j < 8; ++j) tq[j] = f2b(b2f(tq[j]) * (0.03125f * 1.44269504f));
    qf[d] = tq;
  }

  f32x16 o0 = {}, o1 = {}, lacc = {};

  if (parity < nt) {
    stage_k32(Kw, Kg + (long)(parity * 64 + ks * 32) * 3072);
    stage_v32(Kw + 2048, Vg, parity * 64 + ks * 32);
  }

  for (int t = parity; t < nt; t += 2) {
    asm volatile("s_waitcnt vmcnt(0)" ::: "memory");   // tile t resident
    __builtin_amdgcn_sched_barrier(0);
    const char* Kb = (const char*)Kw;
    const char* Vb = Kb + 4096;
    const bf16x8 kf0 = *(const bf16x8*)(Kb + l31 * 128 + 16 * ((0 + h) ^ rs));
    const bf16x8 kf1 = *(const bf16x8*)(Kb + l31 * 128 + 16 * ((2 + h) ^ rs));
    const bf16x8 kf2 = *(const bf16x8*)(Kb + l31 * 128 + 16 * ((4 + h) ^ rs));
    const bf16x8 kf3 = *(const bf16x8*)(Kb + l31 * 128 + 16 * ((6 + h) ^ rs));
    const bf16x8 vf00 = *(const bf16x8*)(Vb + l31 * 128 + 16 * ((0 + h) ^ rs));
    const bf16x8 vf01 = *(const bf16x8*)(Vb + l31 * 128 + 16 * ((2 + h) ^ rs));
    const bf16x8 vf10 = *(const bf16x8*)(Vb + l31 * 128 + 16 * ((4 + h) ^ rs));
    const bf16x8 vf11 = *(const bf16x8*)(Vb + l31 * 128 + 16 * ((6 + h) ^ rs));
    asm volatile("s_waitcnt lgkmcnt(0)" ::: "memory");
    __builtin_amdgcn_sched_barrier(0);
    if (t + 2 < nt) {                                  // re-stage slot for t+2
      stage_k32(Kw, Kg + (long)((t + 2) * 64 + ks * 32) * 3072);
      stage_v32(Kw + 2048, Vg, (t + 2) * 64 + ks * 32);
    }
    f32x16 s = {};
    __builtin_amdgcn_s_setprio(1);
    s = __builtin_amdgcn_mfma_f32_32x32x16_bf16(kf0, qf[0], s, 0, 0, 0);
    s = __builtin_amdgcn_mfma_f32_32x32x16_bf16(kf1, qf[1], s, 0, 0, 0);
    s = __builtin_amdgcn_mfma_f32_32x32x16_bf16(kf2, qf[2], s, 0, 0, 0);
    s = __builtin_amdgcn_mfma_f32_32x32x16_bf16(kf3, qf[3], s, 0, 0, 0);
    __builtin_amdgcn_s_setprio(0);
    if (t == qsuper) {                                 // diagonal causal mask
      const int kb0 = t * 64 + ks * 32 + 4 * h;
#pragma unroll
      for (int r = 0; r < 16; ++r) {
        const int k0 = kb0 + (r & 3) + 8 * (r >> 2);
        if (k0 > q) s[r] = -INFINITY;
      }
    }
#pragma unroll
    for (int r = 0; r < 16; ++r) s[r] = exp2x(s[r]);   // zero-offset softmax
    unsigned P0 = cvtpk(s[0], s[1]),   P1 = cvtpk(s[2], s[3]);
    unsigned P2 = cvtpk(s[4], s[5]),   P3 = cvtpk(s[6], s[7]);
    unsigned P4 = cvtpk(s[8], s[9]),   P5 = cvtpk(s[10], s[11]);
    unsigned P6 = cvtpk(s[12], s[13]), P7 = cvtpk(s[14], s[15]);
    plswap(P0, P2); plswap(P1, P3); plswap(P4, P6); plswap(P5, P7);
    u32x4 f0, f1;
    f0[0] = P0; f0[1] = P1; f0[2] = P2; f0[3] = P3;
    f1[0] = P4; f1[1] = P5; f1[2] = P6; f1[3] = P7;
    const bf16x8 pa0 = __builtin_bit_cast(bf16x8, f0);
    const bf16x8 pa1 = __builtin_bit_cast(bf16x8, f1);
    __builtin_amdgcn_s_setprio(1);
    o0 = __builtin_amdgcn_mfma_f32_32x32x16_bf16(pa0, vf00, o0, 0, 0, 0);
    o0 = __builtin_amdgcn_mfma_f32_32x32x16_bf16(pa1, vf01, o0, 0, 0, 0);
    o1 = __builtin_amdgcn_mfma_f32_32x32x16_bf16(pa0, vf10, o1, 0, 0, 0);
    o1 = __builtin_amdgcn_mfma_f32_32x32x16_bf16(pa1, vf11, o1, 0, 0, 0);
    lacc = __builtin_amdgcn_mfma_f32_32x32x16_bf16(pa0, onesf, lacc, 0, 0, 0);
    lacc = __builtin_amdgcn_mfma_f32_32x32x16_bf16(pa1, onesf, lacc, 0, 0, 0);
    __builtin_amdgcn_s_setprio(0);
  }

  // -------- merge ks halves, write parity partial (unnormalized) --------
  __syncthreads();   // all waves done with KV slots -> OB alias safe
  if (ks == 1) {
#pragma unroll
    for (int r = 0; r < 16; ++r) {
      const int qq = wq * 32 + (r & 3) + 8 * (r >> 2) + 4 * h;
      OB[qq * 64 + l31] = f2b(o0[r]);
      OB[qq * 64 + 32 + l31] = f2b(o1[r]);
    }
    if (l31 == 0) {
#pragma unroll
      for (int r = 0; r < 16; ++r) {
        const int qq = wq * 32 + (r & 3) + 8 * (r >> 2) + 4 * h;
        lAll[qq] = lacc[r];
      }
    }
  }
  __syncthreads();
  if (ks == 0) {
#pragma unroll
    for (int r = 0; r < 16; ++r) {
      const int qq = wq * 32 + (r & 3) + 8 * (r >> 2) + 4 * h;
      const long qr = (long)qsuper * 64 + qq;
      const float v0 = o0[r] + b2f(OB[qq * 64 + l31]);
      const float v1 = o1[r] + b2f(OB[qq * 64 + 32 + l31]);
      Pout[qr * 1024 + head * 64 + l31] = f2b(v0);
      Pout[qr * 1024 + head * 64 + 32 + l31] = f2b(v1);
      if (l31 == 0)
        lbuf[(long)parity * 65536 + head * 4096 + qr] = lacc[r] + lAll[qq];
    }
  }
}

// merge: out = (P0 + P1) / (l0 + l1); P0 aliases out (read-before-write per thread)
__global__ __launch_bounds__(256)
void merge_attn(const short* __restrict__ P0, const short* __restrict__ P1,
                const float* __restrict__ lbuf, short* __restrict__ outp)
{
  const int q = blockIdx.x;
  const int t = threadIdx.x;
  const int head = t >> 4;
  const float l0 = lbuf[head * 4096 + q];
  const float l1 = lbuf[65536 + head * 4096 + q];
  const float inv = 1.f / (l0 + l1);
  const long base = (long)q * 1024 + t * 4;
  short4 a = *(const short4*)(P0 + base);
  short4 b = *(const short4*)(P1 + base);
  short4 o;
  o.x = f2b((b2f(a.x) + b2f(b.x)) * inv);
  o.y = f2b((b2f(a.y) + b2f(b.y)) * inv);
  o.z = f2b((b2f(a.z) + b2f(b.z)) * inv);
  o.w = f2b((b2f(a.w) + b2f(b.w)) * inv);
  *(short4*)(outp + base) = o;
}

// ---------------- launcher ----------------
extern "C" void kernel_launch(void* const* d_in, const int* in_sizes, int n_in,
                              void* d_out, int out_size, void* d_ws, size_t ws_size,
                              hipStream_t stream)
{
  (void)in_sizes; (void)n_in; (void)out_size; (void)ws_size;
  const float* x   = (const float*)d_in[0];
  const float* Wq  = (const float*)d_in[1];
  const float* Wk  = (const float*)d_in[2];
  const float* Wv  = (const float*)d_in[3];
  const float* Wp  = (const float*)d_in[4];
  const float* bp  = (const float*)d_in[5];
  const float* W1  = (const float*)d_in[6];
  const float* b1  = (const float*)d_in[7];
  const float* W2  = (const float*)d_in[8];
  const float* b2  = (const float*)d_in[9];
  const float* g1  = (const float*)d_in[10];
  const float* be1 = (const float*)d_in[11];
  const float* g2  = (const float*)d_in[12];
  const float* be2 = (const float*)d_in[13];
  float* out = (float*)d_out;

  char* ws = (char*)d_ws;
  const size_t MB = 1ull << 20;
  short* WqkvT = (short*)(ws + 0 * MB);    // [3072][1024] bf16, 6MB (dead after QKV gemm)
  short* WpT   = (short*)(ws + 6 * MB);    // 2MB
  short* W1T   = (short*)(ws + 8 * MB);    // 8MB
  short* W2T   = (short*)(ws + 16 * MB);   // 8MB
  short* hbuf  = (short*)(ws + 24 * MB);   // 8MB (h for QKV; P1 partial during attn; h2 after LN2)
  short* qkvb  = (short*)(ws + 32 * MB);   // 24MB qkv; later ff1 spans 32-64MB
  short* attnb = (short*)(ws + 56 * MB);   // 8MB (P0 partial, then merged attn out)
  float* x1    = (float*)(ws + 64 * MB);   // 16MB
  short* Vtb   = (short*)(ws + 64 * MB);   // 8MB (dead before x1 write)
  float* lbuf  = (float*)(ws + 0 * MB);    // [2][16][4096] fp32 = 512KB (aliases dead WqkvT)
  short* P1buf = hbuf;                     // parity-1 partial (hbuf dead during attn)

  prep_all<<<16384, 256, 0, stream>>>(Wq, Wk, Wv, Wp, W1, W2, x, g1, be1,
                                      WqkvT, WpT, W1T, W2T, hbuf);
  gemm256<0><<<dim3(12, 16), 512, 0, stream>>>(hbuf, WqkvT, 3072, 1024, 16,
                                               qkvb, nullptr);
  vtrans<<<dim3(128, 32), dim3(32, 8), 0, stream>>>(qkvb, Vtb);
  attn_fwd7<<<2048, 256, 0, stream>>>(qkvb, Vtb, attnb, P1buf, lbuf);
  merge_attn<<<4096, 256, 0, stream>>>(attnb, P1buf, lbuf, attnb);
  gemm128<1><<<dim3(8, 32), 512, 0, stream>>>(attnb, WpT, 1024, 1024, 16,
                                              nullptr, x1, bp, x);
  layernorm_bf16<<<4096, 256, 0, stream>>>(x1, g2, be2, hbuf);
  gemm256<2><<<dim3(16, 16), 512, 0, stream>>>(hbuf, W1T, 4096, 1024, 16,
                                               qkvb, b1);
  gemm128<1><<<dim3(8, 32), 512, 0, stream>>>(qkvb, W2T, 1024, 4096, 64,
                                              nullptr, out, b2, x1);
}

// Round 14
// 249.319 us; speedup vs baseline: 1.0221x; 1.0221x over previous
//
#include <hip/hip_runtime.h>
#include <cstdint>

typedef __attribute__((ext_vector_type(8))) short bf16x8;
typedef __attribute__((ext_vector_type(4))) float f32x4;
typedef __attribute__((ext_vector_type(16))) float f32x16;
typedef __attribute__((ext_vector_type(4))) unsigned int u32x4;

__device__ __forceinline__ short f2b(float f) {
  unsigned u = __builtin_bit_cast(unsigned, f);
  unsigned r = (u + 0x7fffu + ((u >> 16) & 1u)) >> 16;
  return (short)(unsigned short)r;
}
__device__ __forceinline__ float b2f(short s) {
  unsigned u = ((unsigned)(unsigned short)s) << 16;
  return __builtin_bit_cast(float, u);
}

__device__ __forceinline__ void gload16(void* lds_dst, const void* gsrc) {
  __builtin_amdgcn_global_load_lds(
      (const __attribute__((address_space(1))) void*)gsrc,
      (__attribute__((address_space(3))) void*)lds_dst, 16, 0, 0);
}

__device__ __forceinline__ unsigned cvtpk(float a, float b) {
  unsigned r;
  asm("v_cvt_pk_bf16_f32 %0, %1, %2" : "=v"(r) : "v"(a), "v"(b));
  return r;
}
__device__ __forceinline__ unsigned shflx32(unsigned v) {
  return (unsigned)__shfl_xor((int)v, 32);
}
__device__ __forceinline__ float exp2x(float x) {
  float r;
  asm("v_exp_f32 %0, %1" : "=v"(r) : "v"(x));
  return r;
}

// cross-half swap
__device__ __forceinline__ void plswap(unsigned &a, unsigned &b) {
#if __has_builtin(__builtin_amdgcn_permlane32_swap)
  auto r = __builtin_amdgcn_permlane32_swap((int)a, (int)b, false, false);
  a = (unsigned)r[0];
  b = (unsigned)r[1];
#else
  const bool lo = ((threadIdx.x & 63) < 32);
  unsigned ax = shflx32(a), bx = shflx32(b);
  unsigned na = lo ? a : bx;
  unsigned nb = lo ? ax : b;
  a = na; b = nb;
#endif
}

// ---------------- fused prep: qkv_pack + Wp/W1/W2 transpose + LN1 ----------------
__global__ __launch_bounds__(256)
void prep_all(const float* __restrict__ Wq, const float* __restrict__ Wk,
              const float* __restrict__ Wv, const float* __restrict__ Wp,
              const float* __restrict__ W1, const float* __restrict__ W2,
              const float* __restrict__ x, const float* __restrict__ g1,
              const float* __restrict__ be1,
              short* __restrict__ WqkvT, short* __restrict__ WpT,
              short* __restrict__ W1T, short* __restrict__ W2T,
              short* __restrict__ hbuf)
{
  const int id = blockIdx.x;
  if (id < 12288) {
    __shared__ float tl[32][33];
    const int tx = threadIdx.x & 31;
    const int ty = threadIdx.x >> 5;
    if (id < 3072) {
      const int which = id >> 10;
      const int rem = id & 1023;
      const int head = rem >> 6;
      const int tile = rem & 63;
      const int tc = tile >> 1, td = tile & 1;
      const float* src = (which == 0 ? Wq : which == 1 ? Wk : Wv) + (long)head * 65536;
#pragma unroll
      for (int i2 = 0; i2 < 4; ++i2) {
        int i = ty + i2 * 8;
        tl[i][tx] = src[(long)(tc * 32 + i) * 64 + td * 32 + tx];
      }
      __syncthreads();
      const long base = (long)which * 1024 + head * 64 + td * 32;
#pragma unroll
      for (int i2 = 0; i2 < 4; ++i2) {
        int i = ty + i2 * 8;
        WqkvT[(base + i) * 1024 + tc * 32 + tx] = f2b(tl[tx][i]);
      }
    } else {
      const float* src;
      short* dst;
      int rows, cols, bx, by;
      if (id < 4096) {
        src = Wp; dst = WpT; rows = 1024; cols = 1024;
        const int k = id - 3072; bx = k & 31; by = k >> 5;
      } else if (id < 8192) {
        src = W1; dst = W1T; rows = 1024; cols = 4096;
        const int k = id - 4096; bx = k & 127; by = k >> 7;
      } else {
        src = W2; dst = W2T; rows = 4096; cols = 1024;
        const int k = id - 8192; bx = k & 31; by = k >> 5;
      }
#pragma unroll
      for (int i2 = 0; i2 < 4; ++i2) {
        int i = ty + i2 * 8;
        tl[i][tx] = src[(long)(by * 32 + i) * cols + bx * 32 + tx];
      }
      __syncthreads();
#pragma unroll
      for (int i2 = 0; i2 < 4; ++i2) {
        int i = ty + i2 * 8;
        dst[(long)(bx * 32 + i) * rows + by * 32 + tx] = f2b(tl[tx][i]);
      }
    }
  } else {
    const int row = id - 12288;
    const int t = threadIdx.x;
    const float4 v = ((const float4*)(x + (long)row * 1024))[t];
    float s = v.x + v.y + v.z + v.w;
    float ss = v.x * v.x + v.y * v.y + v.z * v.z + v.w * v.w;
#pragma unroll
    for (int off = 1; off < 64; off <<= 1) {
      s += __shfl_xor(s, off);
      ss += __shfl_xor(ss, off);
    }
    __shared__ float red[8];
    const int wave = t >> 6, lane = t & 63;
    if (lane == 0) { red[wave] = s; red[4 + wave] = ss; }
    __syncthreads();
    s = red[0] + red[1] + red[2] + red[3];
    ss = red[4] + red[5] + red[6] + red[7];
    const float mu = s * (1.f / 1024.f);
    const float rstd = rsqrtf(ss * (1.f / 1024.f) - mu * mu + 1e-5f);
    const float4 gv = ((const float4*)g1)[t];
    const float4 bv = ((const float4*)be1)[t];
    short4 ov;
    ov.x = f2b((v.x - mu) * rstd * gv.x + bv.x);
    ov.y = f2b((v.y - mu) * rstd * gv.y + bv.y);
    ov.z = f2b((v.z - mu) * rstd * gv.z + bv.z);
    ov.w = f2b((v.w - mu) * rstd * gv.w + bv.w);
    *(short4*)(hbuf + (long)row * 1024 + t * 4) = ov;
  }
}

// V part of qkv [4096][3072] -> Vt [16][64][4096] bf16
__global__ void vtrans(const short* __restrict__ qkv, short* __restrict__ Vt)
{
  __shared__ short tl[32][33];
  const int t0 = blockIdx.x * 32;
  const int c0 = blockIdx.y * 32;
  const int head = c0 >> 6, d0 = c0 & 63;
  const int tx = threadIdx.x;
#pragma unroll
  for (int i2 = 0; i2 < 4; ++i2) {
    int i = threadIdx.y + i2 * 8;
    tl[i][tx] = qkv[(long)(t0 + i) * 3072 + 2048 + c0 + tx];
  }
  __syncthreads();
#pragma unroll
  for (int i2 = 0; i2 < 4; ++i2) {
    int i = threadIdx.y + i2 * 8;
    Vt[(long)head * 262144 + (long)(d0 + i) * 4096 + t0 + tx] = tl[tx][i];
  }
}

// ---------------- layernorm (LN2) ----------------
__global__ __launch_bounds__(256)
void layernorm_bf16(const float* __restrict__ x, const float* __restrict__ g,
                    const float* __restrict__ be, short* __restrict__ outp)
{
  const int row = blockIdx.x;
  const int t = threadIdx.x;
  const float4 v = ((const float4*)(x + (long)row * 1024))[t];
  float s = v.x + v.y + v.z + v.w;
  float ss = v.x * v.x + v.y * v.y + v.z * v.z + v.w * v.w;
#pragma unroll
  for (int off = 1; off < 64; off <<= 1) {
    s += __shfl_xor(s, off);
    ss += __shfl_xor(ss, off);
  }
  __shared__ float red[8];
  const int wave = t >> 6, lane = t & 63;
  if (lane == 0) { red[wave] = s; red[4 + wave] = ss; }
  __syncthreads();
  s = red[0] + red[1] + red[2] + red[3];
  ss = red[4] + red[5] + red[6] + red[7];
  const float mu = s * (1.f / 1024.f);
  const float rstd = rsqrtf(ss * (1.f / 1024.f) - mu * mu + 1e-5f);
  const float4 gv = ((const float4*)g)[t];
  const float4 bv = ((const float4*)be)[t];
  short4 ov;
  ov.x = f2b((v.x - mu) * rstd * gv.x + bv.x);
  ov.y = f2b((v.y - mu) * rstd * gv.y + bv.y);
  ov.z = f2b((v.z - mu) * rstd * gv.z + bv.z);
  ov.w = f2b((v.w - mu) * rstd * gv.w + bv.w);
  *(short4*)(outp + (long)row * 1024 + t * 4) = ov;
}

// ---------------- GEMM 128x128, 8-wave, counted-vmcnt pipeline ----------------
template<int EPI>
__global__ __launch_bounds__(512, 2)
void gemm128(const short* __restrict__ A, const short* __restrict__ Bt,
             int N, int K, int NT,
             short* __restrict__ Cb, float* __restrict__ Cf,
             const float* __restrict__ bias, const float* __restrict__ resid)
{
  __shared__ __align__(16) short As[2 * 8192];
  __shared__ __align__(16) short Bs[2 * 8192];
  const int tid = threadIdx.x;
  const int lane = tid & 63;
  const int wave = tid >> 6;
  const int wm = wave >> 2;
  const int wn = wave & 3;
  const int l15 = lane & 15, lg = lane >> 4;

  const int nwg = gridDim.x * gridDim.y;
  const int lin = blockIdx.y * gridDim.x + blockIdx.x;
  const int swz = (lin & 7) * (nwg >> 3) + (lin >> 3);
  const long m0 = (long)(swz / gridDim.x) * 128;
  const long n0 = (long)(swz % gridDim.x) * 128;

  const int rloc = lane >> 3;
  const int csrc = (lane & 7) ^ rloc;
  const short* Ag = A + (m0 + wave * 8 + rloc) * K + csrc * 8;
  const short* Bg = Bt + (n0 + wave * 8 + rloc) * K + csrc * 8;
  const int wbase = wave * 512;

  f32x4 acc[4][2] = {};

#define STAGE128(buf, kt)                                                     \
  do {                                                                        \
    gload16(As + (buf) * 8192 + wbase, Ag + (kt));                            \
    gload16(As + (buf) * 8192 + 4096 + wbase, Ag + (long)64 * K + (kt));      \
    gload16(Bs + (buf) * 8192 + wbase, Bg + (kt));                            \
    gload16(Bs + (buf) * 8192 + 4096 + wbase, Bg + (long)64 * K + (kt));      \
  } while (0)

  STAGE128(0, 0);
  STAGE128(1, 64);
  asm volatile("s_waitcnt vmcnt(4)" ::: "memory");
  __builtin_amdgcn_sched_barrier(0);
  __builtin_amdgcn_s_barrier();
  __builtin_amdgcn_sched_barrier(0);

  const int cA = l15 & 7;
  for (int t = 0; t < NT; ++t) {
    const char* Ab = (const char*)(As + (t & 1) * 8192);
    const char* Bb = (const char*)(Bs + (t & 1) * 8192);
#pragma unroll
    for (int kk = 0; kk < 2; ++kk) {
      bf16x8 af[4], bk[2];
#pragma unroll
      for (int mi = 0; mi < 4; ++mi)
        af[mi] = *(const bf16x8*)(Ab + (wm * 64 + mi * 16 + l15) * 128 + 16 * ((kk * 4 + lg) ^ cA));
#pragma unroll
      for (int ni = 0; ni < 2; ++ni)
        bk[ni] = *(const bf16x8*)(Bb + (wn * 32 + ni * 16 + l15) * 128 + 16 * ((kk * 4 + lg) ^ cA));
      __builtin_amdgcn_s_setprio(1);
#pragma unroll
      for (int mi = 0; mi < 4; ++mi)
#pragma unroll
        for (int ni = 0; ni < 2; ++ni)
          acc[mi][ni] = __builtin_amdgcn_mfma_f32_16x16x32_bf16(af[mi], bk[ni], acc[mi][ni], 0, 0, 0);
      __builtin_amdgcn_s_setprio(0);
    }
    if (t == NT - 1) break;
    __builtin_amdgcn_s_barrier();
    __builtin_amdgcn_sched_barrier(0);
    if (t + 2 < NT) {
      STAGE128(t & 1, (long)(t + 2) * 64);
      asm volatile("s_waitcnt vmcnt(4)" ::: "memory");
    } else {
      asm volatile("s_waitcnt vmcnt(0)" ::: "memory");
    }
    __builtin_amdgcn_sched_barrier(0);
    __builtin_amdgcn_s_barrier();
    __builtin_amdgcn_sched_barrier(0);
  }
#undef STAGE128

#pragma unroll
  for (int mi = 0; mi < 4; ++mi) {
#pragma unroll
    for (int ni = 0; ni < 2; ++ni) {
      const long col = n0 + wn * 32 + ni * 16 + l15;
#pragma unroll
      for (int r = 0; r < 4; ++r) {
        const long row = m0 + wm * 64 + mi * 16 + lg * 4 + r;
        const long idx = row * N + col;
        float v = acc[mi][ni][r];
        if (EPI == 0) {
          Cb[idx] = f2b(v);
        } else {
          Cf[idx] = v + bias[col] + resid[idx];
        }
      }
    }
  }
}

// ---------------- GEMM 256x256, 8-wave, phase-interleaved ----------------
__device__ __forceinline__ void stage256(short* AsB, short* BsB,
                                         const short* Ag, const short* Bg,
                                         long kt, int K, int ldsoff)
{
#pragma unroll
  for (int p = 0; p < 4; ++p)
    gload16(AsB + p * 4096 + ldsoff, Ag + (long)p * 64 * K + kt);
#pragma unroll
  for (int p = 0; p < 4; ++p)
    gload16(BsB + p * 4096 + ldsoff, Bg + (long)p * 64 * K + kt);
}

template<int EPI>
__global__ __launch_bounds__(512, 2)
void gemm256(const short* __restrict__ A, const short* __restrict__ Bt,
             int N, int K, int NT,
             short* __restrict__ Cb, const float* __restrict__ bias)
{
  __shared__ __align__(16) short As[2 * 16384];
  __shared__ __align__(16) short Bs[2 * 16384];
  const int tid = threadIdx.x;
  const int lane = tid & 63;
  const int wave = tid >> 6;
  const int wm = wave >> 2;
  const int wn = wave & 3;
  const int l15 = lane & 15, lg = lane >> 4;

  const int nwg = gridDim.x * gridDim.y;
  const int lin = blockIdx.y * gridDim.x + blockIdx.x;
  const int swz = (lin & 7) * (nwg >> 3) + (lin >> 3);
  const long m0 = (long)(swz / gridDim.x) * 256;
  const long n0 = (long)(swz % gridDim.x) * 256;

  const int trow = tid >> 3;
  const int csrc = (tid & 7) ^ (trow & 7);
  const short* Ag = A + (m0 + trow) * K + csrc * 8;
  const short* Bg = Bt + (n0 + trow) * K + csrc * 8;
  const int ldsoff = wave * 512;

  f32x4 acc[8][4] = {};

  stage256(As, Bs, Ag, Bg, 0, K, ldsoff);
  asm volatile("s_waitcnt vmcnt(0)" ::: "memory");
  __builtin_amdgcn_sched_barrier(0);
  __builtin_amdgcn_s_barrier();
  __builtin_amdgcn_sched_barrier(0);

  const int cA = l15 & 7;
  for (int t = 0; t < NT; ++t) {
    const char* Ab = (const char*)(As + (t & 1) * 16384);
    const char* Bb = (const char*)(Bs + (t & 1) * 16384);
    short* Asn = As + ((t + 1) & 1) * 16384;
    short* Bsn = Bs + ((t + 1) & 1) * 16384;
    const bool more = (t + 1 < NT);
    const long ktn = (long)(t + 1) * 64;
    bf16x8 bk[4];
#pragma unroll
    for (int ph = 0; ph < 4; ++ph) {
      const int kk = ph >> 1;
      const int mh = (ph & 1) * 4;
      bf16x8 af[4];
#pragma unroll
      for (int mi = 0; mi < 4; ++mi)
        af[mi] = *(const bf16x8*)(Ab + (wm * 128 + (mh + mi) * 16 + l15) * 128 + 16 * ((kk * 4 + lg) ^ cA));
      if ((ph & 1) == 0) {
#pragma unroll
        for (int ni = 0; ni < 4; ++ni)
          bk[ni] = *(const bf16x8*)(Bb + (wn * 64 + ni * 16 + l15) * 128 + 16 * ((kk * 4 + lg) ^ cA));
      }
      if (more && ph == 0) {
#pragma unroll
        for (int p = 0; p < 4; ++p)
          gload16(Asn + p * 4096 + ldsoff, Ag + (long)p * 64 * K + ktn);
      }
      if (more && ph == 1) {
#pragma unroll
        for (int p = 0; p < 4; ++p)
          gload16(Bsn + p * 4096 + ldsoff, Bg + (long)p * 64 * K + ktn);
      }
      __builtin_amdgcn_s_barrier();
      asm volatile("s_waitcnt lgkmcnt(0)" ::: "memory");
      __builtin_amdgcn_sched_barrier(0);
      __builtin_amdgcn_s_setprio(1);
#pragma unroll
      for (int mi = 0; mi < 4; ++mi)
#pragma unroll
        for (int ni = 0; ni < 4; ++ni)
          acc[mh + mi][ni] = __builtin_amdgcn_mfma_f32_16x16x32_bf16(af[mi], bk[ni], acc[mh + mi][ni], 0, 0, 0);
      __builtin_amdgcn_s_setprio(0);
      if (ph == 3 && more) {
        asm volatile("s_waitcnt vmcnt(0)" ::: "memory");
        __builtin_amdgcn_sched_barrier(0);
      }
      __builtin_amdgcn_s_barrier();
      __builtin_amdgcn_sched_barrier(0);
    }
  }

#pragma unroll
  for (int mi = 0; mi < 8; ++mi) {
#pragma unroll
    for (int ni = 0; ni < 4; ++ni) {
      const long col = n0 + wn * 64 + ni * 16 + l15;
      const float bb = (EPI == 2) ? bias[col] : 0.f;
#pragma unroll
      for (int r = 0; r < 4; ++r) {
        const long row = m0 + wm * 128 + mi * 16 + lg * 4 + r;
        float v = acc[mi][ni][r];
        if (EPI == 2) { v += bb; v = v > 0.f ? v : 0.f; }
        Cb[row * N + col] = f2b(v);
      }
    }
  }
}

// ---------------- flash attention v8: simultaneous ladder ---------------------
// 512 blocks = (head 16, bx 32); block processes BOTH qsupers A=bx and B=63-bx
// in ONE kv loop: staged tile t feeds B always, plus A when t<=A. Staged tiles
// per block 64-bx (avg 48.5 vs v6's 65) and each ds_read fragment feeds up to
// 2 q-blocks -> DS+TA traffic per compute x0.75. Compute per block uniform (65
// units). Single-slot wave-private ring; no-max softmax; l via ones-MFMA.
__device__ __forceinline__ void stage_k32(short* lds, const short* gRowBase)
{
  const int lane = threadIdx.x & 63;
  const int rloc = lane >> 3;
  const int cs = (lane & 7) ^ rloc;
#pragma unroll
  for (int p = 0; p < 4; ++p)
    gload16(lds + p * 512, gRowBase + (long)(p * 8 + rloc) * 3072 + cs * 8);
}
__device__ __forceinline__ void stage_v32(short* lds, const short* vHeadBase, int t0)
{
  const int lane = threadIdx.x & 63;
  const int rloc = lane >> 3;
  const int cs = (lane & 7) ^ rloc;
#pragma unroll
  for (int p = 0; p < 4; ++p) {
    const int row = p * 8 + rloc;
    const int d = row + ((cs & 4) << 3);
    gload16(lds + p * 512, vHeadBase + (long)d * 4096 + t0 + (cs & 3) * 8);
  }
}

__global__ __launch_bounds__(256)
void attn_fwd8(const short* __restrict__ qkv, const short* __restrict__ Vt,
               short* __restrict__ outp)
{
  __shared__ __align__(16) short POOL[4 * 4096];  // 32KB: per-wave 1 slot (K|V)
  __shared__ float lAll[64];
  short* const OB = POOL;                         // aliased merge scratch

  const int tid = threadIdx.x;
  const int lane = tid & 63;
  const int wave = tid >> 6;      // 0..3
  const int wq = wave & 1;
  const int ks = wave >> 1;
  const int l31 = lane & 31;
  const int h = lane >> 5;
  const int rs = l31 & 7;

  const int id = blockIdx.x;                     // 0..511
  const int head = ((id & 7) << 1) | (id >> 8);  // head-locality per XCD
  const int bx = (id >> 3) & 31;
  const int qsA = bx, qsB = 63 - bx;             // A < B

  const short* Qg = qkv + head * 64;
  const short* Kg = qkv + 1024 + head * 64;
  const short* Vg = Vt + (long)head * 262144;

  short* Kw = POOL + wave * 4096;                // wave-private slot

  bf16x8 onesf;
#pragma unroll
  for (int j = 0; j < 8; ++j) onesf[j] = (short)0x3F80;

  const int q0A = qsA * 64 + wq * 32, qA = q0A + l31;
  const int q0B = qsB * 64 + wq * 32, qB = q0B + l31;
  const int nt = qsB + 1;

  bf16x8 qfA[4], qfB[4];
#pragma unroll
  for (int d = 0; d < 4; ++d) {
    bf16x8 ta = *(const bf16x8*)(Qg + (long)qA * 3072 + d * 16 + h * 8);
    bf16x8 tb = *(const bf16x8*)(Qg + (long)qB * 3072 + d * 16 + h * 8);
#pragma unroll
    for (int j = 0; j < 8; ++j) {
      ta[j] = f2b(b2f(ta[j]) * (0.03125f * 1.44269504f));
      tb[j] = f2b(b2f(tb[j]) * (0.03125f * 1.44269504f));
    }
    qfA[d] = ta;
    qfB[d] = tb;
  }

  f32x16 oA0 = {}, oA1 = {}, lA = {};
  f32x16 oB0 = {}, oB1 = {}, lB = {};

  // prologue: stage tile 0
  stage_k32(Kw, Kg + (long)(ks * 32) * 3072);
  stage_v32(Kw + 2048, Vg, ks * 32);

  for (int t = 0; t < nt; ++t) {
    asm volatile("s_waitcnt vmcnt(0)" ::: "memory");   // tile t resident
    __builtin_amdgcn_sched_barrier(0);
    const char* Kb = (const char*)Kw;
    const char* Vb = Kb + 4096;
    const bf16x8 kf0 = *(const bf16x8*)(Kb + l31 * 128 + 16 * ((0 + h) ^ rs));
    const bf16x8 kf1 = *(const bf16x8*)(Kb + l31 * 128 + 16 * ((2 + h) ^ rs));
    const bf16x8 kf2 = *(const bf16x8*)(Kb + l31 * 128 + 16 * ((4 + h) ^ rs));
    const bf16x8 kf3 = *(const bf16x8*)(Kb + l31 * 128 + 16 * ((6 + h) ^ rs));
    const bf16x8 vf00 = *(const bf16x8*)(Vb + l31 * 128 + 16 * ((0 + h) ^ rs));
    const bf16x8 vf01 = *(const bf16x8*)(Vb + l31 * 128 + 16 * ((2 + h) ^ rs));
    const bf16x8 vf10 = *(const bf16x8*)(Vb + l31 * 128 + 16 * ((4 + h) ^ rs));
    const bf16x8 vf11 = *(const bf16x8*)(Vb + l31 * 128 + 16 * ((6 + h) ^ rs));
    asm volatile("s_waitcnt lgkmcnt(0)" ::: "memory"); // frags in registers
    __builtin_amdgcn_sched_barrier(0);
    if (t + 1 < nt) {                                  // re-stage slot for t+1
      stage_k32(Kw, Kg + (long)((t + 1) * 64 + ks * 32) * 3072);
      stage_v32(Kw + 2048, Vg, (t + 1) * 64 + ks * 32);
    }
    const bool doA = (t <= qsA);
    // QK chains (B always; A when in range) — independent, interleavable
    f32x16 sB = {}, sA = {};
    __builtin_amdgcn_s_setprio(1);
    sB = __builtin_amdgcn_mfma_f32_32x32x16_bf16(kf0, qfB[0], sB, 0, 0, 0);
    sB = __builtin_amdgcn_mfma_f32_32x32x16_bf16(kf1, qfB[1], sB, 0, 0, 0);
    sB = __builtin_amdgcn_mfma_f32_32x32x16_bf16(kf2, qfB[2], sB, 0, 0, 0);
    sB = __builtin_amdgcn_mfma_f32_32x32x16_bf16(kf3, qfB[3], sB, 0, 0, 0);
    if (doA) {
      sA = __builtin_amdgcn_mfma_f32_32x32x16_bf16(kf0, qfA[0], sA, 0, 0, 0);
      sA = __builtin_amdgcn_mfma_f32_32x32x16_bf16(kf1, qfA[1], sA, 0, 0, 0);
      sA = __builtin_amdgcn_mfma_f32_32x32x16_bf16(kf2, qfA[2], sA, 0, 0, 0);
      sA = __builtin_amdgcn_mfma_f32_32x32x16_bf16(kf3, qfA[3], sA, 0, 0, 0);
    }
    __builtin_amdgcn_s_setprio(0);
    // ---- B path ----
    if (t == qsB) {
      const int kb0 = t * 64 + ks * 32 + 4 * h;
#pragma unroll
      for (int r = 0; r < 16; ++r) {
        const int k0 = kb0 + (r & 3) + 8 * (r >> 2);
        if (k0 > qB) sB[r] = -INFINITY;
      }
    }
#pragma unroll
    for (int r = 0; r < 16; ++r) sB[r] = exp2x(sB[r]);
    {
      unsigned P0 = cvtpk(sB[0], sB[1]),   P1 = cvtpk(sB[2], sB[3]);
      unsigned P2 = cvtpk(sB[4], sB[5]),   P3 = cvtpk(sB[6], sB[7]);
      unsigned P4 = cvtpk(sB[8], sB[9]),   P5 = cvtpk(sB[10], sB[11]);
      unsigned P6 = cvtpk(sB[12], sB[13]), P7 = cvtpk(sB[14], sB[15]);
      plswap(P0, P2); plswap(P1, P3); plswap(P4, P6); plswap(P5, P7);
      u32x4 f0, f1;
      f0[0] = P0; f0[1] = P1; f0[2] = P2; f0[3] = P3;
      f1[0] = P4; f1[1] = P5; f1[2] = P6; f1[3] = P7;
      const bf16x8 pa0 = __builtin_bit_cast(bf16x8, f0);
      const bf16x8 pa1 = __builtin_bit_cast(bf16x8, f1);
      __builtin_amdgcn_s_setprio(1);
      oB0 = __builtin_amdgcn_mfma_f32_32x32x16_bf16(pa0, vf00, oB0, 0, 0, 0);
      oB0 = __builtin_amdgcn_mfma_f32_32x32x16_bf16(pa1, vf01, oB0, 0, 0, 0);
      oB1 = __builtin_amdgcn_mfma_f32_32x32x16_bf16(pa0, vf10, oB1, 0, 0, 0);
      oB1 = __builtin_amdgcn_mfma_f32_32x32x16_bf16(pa1, vf11, oB1, 0, 0, 0);
      lB = __builtin_amdgcn_mfma_f32_32x32x16_bf16(pa0, onesf, lB, 0, 0, 0);
      lB = __builtin_amdgcn_mfma_f32_32x32x16_bf16(pa1, onesf, lB, 0, 0, 0);
      __builtin_amdgcn_s_setprio(0);
    }
    // ---- A path ----
    if (doA) {
      if (t == qsA) {
        const int kb0 = t * 64 + ks * 32 + 4 * h;
#pragma unroll
        for (int r = 0; r < 16; ++r) {
          const int k0 = kb0 + (r & 3) + 8 * (r >> 2);
          if (k0 > qA) sA[r] = -INFINITY;
        }
      }
#pragma unroll
      for (int r = 0; r < 16; ++r) sA[r] = exp2x(sA[r]);
      unsigned P0 = cvtpk(sA[0], sA[1]),   P1 = cvtpk(sA[2], sA[3]);
      unsigned P2 = cvtpk(sA[4], sA[5]),   P3 = cvtpk(sA[6], sA[7]);
      unsigned P4 = cvtpk(sA[8], sA[9]),   P5 = cvtpk(sA[10], sA[11]);
      unsigned P6 = cvtpk(sA[12], sA[13]), P7 = cvtpk(sA[14], sA[15]);
      plswap(P0, P2); plswap(P1, P3); plswap(P4, P6); plswap(P5, P7);
      u32x4 f0, f1;
      f0[0] = P0; f0[1] = P1; f0[2] = P2; f0[3] = P3;
      f1[0] = P4; f1[1] = P5; f1[2] = P6; f1[3] = P7;
      const bf16x8 pa0 = __builtin_bit_cast(bf16x8, f0);
      const bf16x8 pa1 = __builtin_bit_cast(bf16x8, f1);
      __builtin_amdgcn_s_setprio(1);
      oA0 = __builtin_amdgcn_mfma_f32_32x32x16_bf16(pa0, vf00, oA0, 0, 0, 0);
      oA0 = __builtin_amdgcn_mfma_f32_32x32x16_bf16(pa1, vf01, oA0, 0, 0, 0);
      oA1 = __builtin_amdgcn_mfma_f32_32x32x16_bf16(pa0, vf10, oA1, 0, 0, 0);
      oA1 = __builtin_amdgcn_mfma_f32_32x32x16_bf16(pa1, vf11, oA1, 0, 0, 0);
      lA = __builtin_amdgcn_mfma_f32_32x32x16_bf16(pa0, onesf, lA, 0, 0, 0);
      lA = __builtin_amdgcn_mfma_f32_32x32x16_bf16(pa1, onesf, lA, 0, 0, 0);
      __builtin_amdgcn_s_setprio(0);
    }
  }

  // -------- merges: B set, then A set (OB/lAll reused, barrier-guarded) ----
  __syncthreads();   // all waves done with KV slots -> OB alias safe
  if (ks == 1) {
#pragma unroll
    for (int r = 0; r < 16; ++r) {
      const int qq = wq * 32 + (r & 3) + 8 * (r >> 2) + 4 * h;
      OB[qq * 64 + l31] = f2b(oB0[r]);
      OB[qq * 64 + 32 + l31] = f2b(oB1[r]);
    }
    if (l31 == 0) {
#pragma unroll
      for (int r = 0; r < 16; ++r) {
        const int qq = wq * 32 + (r & 3) + 8 * (r >> 2) + 4 * h;
        lAll[qq] = lB[r];
      }
    }
  }
  __syncthreads();
  if (ks == 0) {
#pragma unroll
    for (int r = 0; r < 16; ++r) {
      const int qq = wq * 32 + (r & 3) + 8 * (r >> 2) + 4 * h;
      const float inv = 1.f / (lB[r] + lAll[qq]);
      const long qr = (long)qsB * 64 + qq;
      const float v0 = oB0[r] + b2f(OB[qq * 64 + l31]);
      const float v1 = oB1[r] + b2f(OB[qq * 64 + 32 + l31]);
      outp[qr * 1024 + head * 64 + l31] = f2b(v0 * inv);
      outp[qr * 1024 + head * 64 + 32 + l31] = f2b(v1 * inv);
    }
  }
  __syncthreads();
  if (ks == 1) {
#pragma unroll
    for (int r = 0; r < 16; ++r) {
      const int qq = wq * 32 + (r & 3) + 8 * (r >> 2) + 4 * h;
      OB[qq * 64 + l31] = f2b(oA0[r]);
      OB[qq * 64 + 32 + l31] = f2b(oA1[r]);
    }
    if (l31 == 0) {
#pragma unroll
      for (int r = 0; r < 16; ++r) {
        const int qq = wq * 32 + (r & 3) + 8 * (r >> 2) + 4 * h;
        lAll[qq] = lA[r];
      }
    }
  }
  __syncthreads();
  if (ks == 0) {
#pragma unroll
    for (int r = 0; r < 16; ++r) {
      const int qq = wq * 32 + (r & 3) + 8 * (r >> 2) + 4 * h;
      const float inv = 1.f / (lA[r] + lAll[qq]);
      const long qr = (long)qsA * 64 + qq;
      const float v0 = oA0[r] + b2f(OB[qq * 64 + l31]);
      const float v1 = oA1[r] + b2f(OB[qq * 64 + 32 + l31]);
      outp[qr * 1024 + head * 64 + l31] = f2b(v0 * inv);
      outp[qr * 1024 + head * 64 + 32 + l31] = f2b(v1 * inv);
    }
  }
}

// ---------------- launcher ----------------
extern "C" void kernel_launch(void* const* d_in, const int* in_sizes, int n_in,
                              void* d_out, int out_size, void* d_ws, size_t ws_size,
                              hipStream_t stream)
{
  (void)in_sizes; (void)n_in; (void)out_size; (void)ws_size;
  const float* x   = (const float*)d_in[0];
  const float* Wq  = (const float*)d_in[1];
  const float* Wk  = (const float*)d_in[2];
  const float* Wv  = (const float*)d_in[3];
  const float* Wp  = (const float*)d_in[4];
  const float* bp  = (const float*)d_in[5];
  const float* W1  = (const float*)d_in[6];
  const float* b1  = (const float*)d_in[7];
  const float* W2  = (const float*)d_in[8];
  const float* b2  = (const float*)d_in[9];
  const float* g1  = (const float*)d_in[10];
  const float* be1 = (const float*)d_in[11];
  const float* g2  = (const float*)d_in[12];
  const float* be2 = (const float*)d_in[13];
  float* out = (float*)d_out;

  char* ws = (char*)d_ws;
  const size_t MB = 1ull << 20;
  short* WqkvT = (short*)(ws + 0 * MB);    // [3072][1024] bf16, 6MB
  short* WpT   = (short*)(ws + 6 * MB);    // 2MB
  short* W1T   = (short*)(ws + 8 * MB);    // 8MB
  short* W2T   = (short*)(ws + 16 * MB);   // 8MB
  short* hbuf  = (short*)(ws + 24 * MB);   // 8MB (h, then h2)
  short* qkvb  = (short*)(ws + 32 * MB);   // 24MB qkv; later ff1 spans 32-64MB
  short* attnb = (short*)(ws + 56 * MB);   // 8MB
  float* x1    = (float*)(ws + 64 * MB);   // 16MB
  short* Vtb   = (short*)(ws + 64 * MB);   // 8MB (dead before x1 write)

  prep_all<<<16384, 256, 0, stream>>>(Wq, Wk, Wv, Wp, W1, W2, x, g1, be1,
                                      WqkvT, WpT, W1T, W2T, hbuf);
  gemm256<0><<<dim3(12, 16), 512, 0, stream>>>(hbuf, WqkvT, 3072, 1024, 16,
                                               qkvb, nullptr);
  vtrans<<<dim3(128, 32), dim3(32, 8), 0, stream>>>(qkvb, Vtb);
  attn_fwd8<<<512, 256, 0, stream>>>(qkvb, Vtb, attnb);
  gemm128<1><<<dim3(8, 32), 512, 0, stream>>>(attnb, WpT, 1024, 1024, 16,
                                              nullptr, x1, bp, x);
  layernorm_bf16<<<4096, 256, 0, stream>>>(x1, g2, be2, hbuf);
  gemm256<2><<<dim3(16, 16), 512, 0, stream>>>(hbuf, W1T, 4096, 1024, 16,
                                               qkvb, b1);
  gemm128<1><<<dim3(8, 32), 512, 0, stream>>>(qkvb, W2T, 1024, 4096, 64,
                                              nullptr, out, b2, x1);
}

// Round 15
// 231.504 us; speedup vs baseline: 1.1008x; 1.0770x over previous
//
#include <hip/hip_runtime.h>
#include <cstdint>

typedef __attribute__((ext_vector_type(8))) short bf16x8;
typedef __attribute__((ext_vector_type(4))) float f32x4;
typedef __attribute__((ext_vector_type(16))) float f32x16;
typedef __attribute__((ext_vector_type(4))) unsigned int u32x4;

__device__ __forceinline__ short f2b(float f) {
  unsigned u = __builtin_bit_cast(unsigned, f);
  unsigned r = (u + 0x7fffu + ((u >> 16) & 1u)) >> 16;
  return (short)(unsigned short)r;
}
__device__ __forceinline__ float b2f(short s) {
  unsigned u = ((unsigned)(unsigned short)s) << 16;
  return __builtin_bit_cast(float, u);
}

__device__ __forceinline__ void gload16(void* lds_dst, const void* gsrc) {
  __builtin_amdgcn_global_load_lds(
      (const __attribute__((address_space(1))) void*)gsrc,
      (__attribute__((address_space(3))) void*)lds_dst, 16, 0, 0);
}

__device__ __forceinline__ unsigned cvtpk(float a, float b) {
  unsigned r;
  asm("v_cvt_pk_bf16_f32 %0, %1, %2" : "=v"(r) : "v"(a), "v"(b));
  return r;
}
__device__ __forceinline__ unsigned shflx32(unsigned v) {
  return (unsigned)__shfl_xor((int)v, 32);
}
__device__ __forceinline__ float exp2x(float x) {
  float r;
  asm("v_exp_f32 %0, %1" : "=v"(r) : "v"(x));
  return r;
}

// cross-half swap
__device__ __forceinline__ void plswap(unsigned &a, unsigned &b) {
#if __has_builtin(__builtin_amdgcn_permlane32_swap)
  auto r = __builtin_amdgcn_permlane32_swap((int)a, (int)b, false, false);
  a = (unsigned)r[0];
  b = (unsigned)r[1];
#else
  const bool lo = ((threadIdx.x & 63) < 32);
  unsigned ax = shflx32(a), bx = shflx32(b);
  unsigned na = lo ? a : bx;
  unsigned nb = lo ? ax : b;
  a = na; b = nb;
#endif
}

// ---------------- fused prep: qkv_pack + Wp/W1/W2 transpose + LN1 ----------------
__global__ __launch_bounds__(256)
void prep_all(const float* __restrict__ Wq, const float* __restrict__ Wk,
              const float* __restrict__ Wv, const float* __restrict__ Wp,
              const float* __restrict__ W1, const float* __restrict__ W2,
              const float* __restrict__ x, const float* __restrict__ g1,
              const float* __restrict__ be1,
              short* __restrict__ WqkvT, short* __restrict__ WpT,
              short* __restrict__ W1T, short* __restrict__ W2T,
              short* __restrict__ hbuf)
{
  const int id = blockIdx.x;
  if (id < 12288) {
    __shared__ float tl[32][33];
    const int tx = threadIdx.x & 31;
    const int ty = threadIdx.x >> 5;
    if (id < 3072) {
      const int which = id >> 10;
      const int rem = id & 1023;
      const int head = rem >> 6;
      const int tile = rem & 63;
      const int tc = tile >> 1, td = tile & 1;
      const float* src = (which == 0 ? Wq : which == 1 ? Wk : Wv) + (long)head * 65536;
#pragma unroll
      for (int i2 = 0; i2 < 4; ++i2) {
        int i = ty + i2 * 8;
        tl[i][tx] = src[(long)(tc * 32 + i) * 64 + td * 32 + tx];
      }
      __syncthreads();
      const long base = (long)which * 1024 + head * 64 + td * 32;
#pragma unroll
      for (int i2 = 0; i2 < 4; ++i2) {
        int i = ty + i2 * 8;
        WqkvT[(base + i) * 1024 + tc * 32 + tx] = f2b(tl[tx][i]);
      }
    } else {
      const float* src;
      short* dst;
      int rows, cols, bx, by;
      if (id < 4096) {
        src = Wp; dst = WpT; rows = 1024; cols = 1024;
        const int k = id - 3072; bx = k & 31; by = k >> 5;
      } else if (id < 8192) {
        src = W1; dst = W1T; rows = 1024; cols = 4096;
        const int k = id - 4096; bx = k & 127; by = k >> 7;
      } else {
        src = W2; dst = W2T; rows = 4096; cols = 1024;
        const int k = id - 8192; bx = k & 31; by = k >> 5;
      }
#pragma unroll
      for (int i2 = 0; i2 < 4; ++i2) {
        int i = ty + i2 * 8;
        tl[i][tx] = src[(long)(by * 32 + i) * cols + bx * 32 + tx];
      }
      __syncthreads();
#pragma unroll
      for (int i2 = 0; i2 < 4; ++i2) {
        int i = ty + i2 * 8;
        dst[(long)(bx * 32 + i) * rows + by * 32 + tx] = f2b(tl[tx][i]);
      }
    }
  } else {
    const int row = id - 12288;
    const int t = threadIdx.x;
    const float4 v = ((const float4*)(x + (long)row * 1024))[t];
    float s = v.x + v.y + v.z + v.w;
    float ss = v.x * v.x + v.y * v.y + v.z * v.z + v.w * v.w;
#pragma unroll
    for (int off = 1; off < 64; off <<= 1) {
      s += __shfl_xor(s, off);
      ss += __shfl_xor(ss, off);
    }
    __shared__ float red[8];
    const int wave = t >> 6, lane = t & 63;
    if (lane == 0) { red[wave] = s; red[4 + wave] = ss; }
    __syncthreads();
    s = red[0] + red[1] + red[2] + red[3];
    ss = red[4] + red[5] + red[6] + red[7];
    const float mu = s * (1.f / 1024.f);
    const float rstd = rsqrtf(ss * (1.f / 1024.f) - mu * mu + 1e-5f);
    const float4 gv = ((const float4*)g1)[t];
    const float4 bv = ((const float4*)be1)[t];
    short4 ov;
    ov.x = f2b((v.x - mu) * rstd * gv.x + bv.x);
    ov.y = f2b((v.y - mu) * rstd * gv.y + bv.y);
    ov.z = f2b((v.z - mu) * rstd * gv.z + bv.z);
    ov.w = f2b((v.w - mu) * rstd * gv.w + bv.w);
    *(short4*)(hbuf + (long)row * 1024 + t * 4) = ov;
  }
}

// V part of qkv [4096][3072] -> Vt [16][64][4096] bf16
__global__ void vtrans(const short* __restrict__ qkv, short* __restrict__ Vt)
{
  __shared__ short tl[32][33];
  const int t0 = blockIdx.x * 32;
  const int c0 = blockIdx.y * 32;
  const int head = c0 >> 6, d0 = c0 & 63;
  const int tx = threadIdx.x;
#pragma unroll
  for (int i2 = 0; i2 < 4; ++i2) {
    int i = threadIdx.y + i2 * 8;
    tl[i][tx] = qkv[(long)(t0 + i) * 3072 + 2048 + c0 + tx];
  }
  __syncthreads();
#pragma unroll
  for (int i2 = 0; i2 < 4; ++i2) {
    int i = threadIdx.y + i2 * 8;
    Vt[(long)head * 262144 + (long)(d0 + i) * 4096 + t0 + tx] = tl[tx][i];
  }
}

// ---------------- layernorm (LN2) ----------------
__global__ __launch_bounds__(256)
void layernorm_bf16(const float* __restrict__ x, const float* __restrict__ g,
                    const float* __restrict__ be, short* __restrict__ outp)
{
  const int row = blockIdx.x;
  const int t = threadIdx.x;
  const float4 v = ((const float4*)(x + (long)row * 1024))[t];
  float s = v.x + v.y + v.z + v.w;
  float ss = v.x * v.x + v.y * v.y + v.z * v.z + v.w * v.w;
#pragma unroll
  for (int off = 1; off < 64; off <<= 1) {
    s += __shfl_xor(s, off);
    ss += __shfl_xor(ss, off);
  }
  __shared__ float red[8];
  const int wave = t >> 6, lane = t & 63;
  if (lane == 0) { red[wave] = s; red[4 + wave] = ss; }
  __syncthreads();
  s = red[0] + red[1] + red[2] + red[3];
  ss = red[4] + red[5] + red[6] + red[7];
  const float mu = s * (1.f / 1024.f);
  const float rstd = rsqrtf(ss * (1.f / 1024.f) - mu * mu + 1e-5f);
  const float4 gv = ((const float4*)g)[t];
  const float4 bv = ((const float4*)be)[t];
  short4 ov;
  ov.x = f2b((v.x - mu) * rstd * gv.x + bv.x);
  ov.y = f2b((v.y - mu) * rstd * gv.y + bv.y);
  ov.z = f2b((v.z - mu) * rstd * gv.z + bv.z);
  ov.w = f2b((v.w - mu) * rstd * gv.w + bv.w);
  *(short4*)(outp + (long)row * 1024 + t * 4) = ov;
}

// ---------------- GEMM 128x128, 8-wave, counted-vmcnt pipeline ----------------
template<int EPI>
__global__ __launch_bounds__(512, 2)
void gemm128(const short* __restrict__ A, const short* __restrict__ Bt,
             int N, int K, int NT,
             short* __restrict__ Cb, float* __restrict__ Cf,
             const float* __restrict__ bias, const float* __restrict__ resid)
{
  __shared__ __align__(16) short As[2 * 8192];
  __shared__ __align__(16) short Bs[2 * 8192];
  const int tid = threadIdx.x;
  const int lane = tid & 63;
  const int wave = tid >> 6;
  const int wm = wave >> 2;
  const int wn = wave & 3;
  const int l15 = lane & 15, lg = lane >> 4;

  const int nwg = gridDim.x * gridDim.y;
  const int lin = blockIdx.y * gridDim.x + blockIdx.x;
  const int swz = (lin & 7) * (nwg >> 3) + (lin >> 3);
  const long m0 = (long)(swz / gridDim.x) * 128;
  const long n0 = (long)(swz % gridDim.x) * 128;

  const int rloc = lane >> 3;
  const int csrc = (lane & 7) ^ rloc;
  const short* Ag = A + (m0 + wave * 8 + rloc) * K + csrc * 8;
  const short* Bg = Bt + (n0 + wave * 8 + rloc) * K + csrc * 8;
  const int wbase = wave * 512;

  f32x4 acc[4][2] = {};

#define STAGE128(buf, kt)                                                     \
  do {                                                                        \
    gload16(As + (buf) * 8192 + wbase, Ag + (kt));                            \
    gload16(As + (buf) * 8192 + 4096 + wbase, Ag + (long)64 * K + (kt));      \
    gload16(Bs + (buf) * 8192 + wbase, Bg + (kt));                            \
    gload16(Bs + (buf) * 8192 + 4096 + wbase, Bg + (long)64 * K + (kt));      \
  } while (0)

  STAGE128(0, 0);
  STAGE128(1, 64);
  asm volatile("s_waitcnt vmcnt(4)" ::: "memory");
  __builtin_amdgcn_sched_barrier(0);
  __builtin_amdgcn_s_barrier();
  __builtin_amdgcn_sched_barrier(0);

  const int cA = l15 & 7;
  for (int t = 0; t < NT; ++t) {
    const char* Ab = (const char*)(As + (t & 1) * 8192);
    const char* Bb = (const char*)(Bs + (t & 1) * 8192);
#pragma unroll
    for (int kk = 0; kk < 2; ++kk) {
      bf16x8 af[4], bk[2];
#pragma unroll
      for (int mi = 0; mi < 4; ++mi)
        af[mi] = *(const bf16x8*)(Ab + (wm * 64 + mi * 16 + l15) * 128 + 16 * ((kk * 4 + lg) ^ cA));
#pragma unroll
      for (int ni = 0; ni < 2; ++ni)
        bk[ni] = *(const bf16x8*)(Bb + (wn * 32 + ni * 16 + l15) * 128 + 16 * ((kk * 4 + lg) ^ cA));
      __builtin_amdgcn_s_setprio(1);
#pragma unroll
      for (int mi = 0; mi < 4; ++mi)
#pragma unroll
        for (int ni = 0; ni < 2; ++ni)
          acc[mi][ni] = __builtin_amdgcn_mfma_f32_16x16x32_bf16(af[mi], bk[ni], acc[mi][ni], 0, 0, 0);
      __builtin_amdgcn_s_setprio(0);
    }
    if (t == NT - 1) break;
    __builtin_amdgcn_s_barrier();
    __builtin_amdgcn_sched_barrier(0);
    if (t + 2 < NT) {
      STAGE128(t & 1, (long)(t + 2) * 64);
      asm volatile("s_waitcnt vmcnt(4)" ::: "memory");
    } else {
      asm volatile("s_waitcnt vmcnt(0)" ::: "memory");
    }
    __builtin_amdgcn_sched_barrier(0);
    __builtin_amdgcn_s_barrier();
    __builtin_amdgcn_sched_barrier(0);
  }
#undef STAGE128

#pragma unroll
  for (int mi = 0; mi < 4; ++mi) {
#pragma unroll
    for (int ni = 0; ni < 2; ++ni) {
      const long col = n0 + wn * 32 + ni * 16 + l15;
#pragma unroll
      for (int r = 0; r < 4; ++r) {
        const long row = m0 + wm * 64 + mi * 16 + lg * 4 + r;
        const long idx = row * N + col;
        float v = acc[mi][ni][r];
        if (EPI == 0) {
          Cb[idx] = f2b(v);
        } else {
          Cf[idx] = v + bias[col] + resid[idx];
        }
      }
    }
  }
}

// ---------------- GEMM 128x128 split-K2: bf16 partials, one dispatch ---------
// grid (8, 64): y = mtile(0..31) + 32*half; k-slice = half*2048, NT=32.
// half 0 -> p0, half 1 -> p1. Same pipeline as gemm128; 512 blocks = 2/CU.
__global__ __launch_bounds__(512, 2)
void gemm128sk(const short* __restrict__ A, const short* __restrict__ Bt,
               int N, int K, int NT,
               short* __restrict__ p0, short* __restrict__ p1)
{
  __shared__ __align__(16) short As[2 * 8192];
  __shared__ __align__(16) short Bs[2 * 8192];
  const int tid = threadIdx.x;
  const int lane = tid & 63;
  const int wave = tid >> 6;
  const int wm = wave >> 2;
  const int wn = wave & 3;
  const int l15 = lane & 15, lg = lane >> 4;

  const int nwg = gridDim.x * gridDim.y;          // 512
  const int lin = blockIdx.y * gridDim.x + blockIdx.x;
  const int swz = (lin & 7) * (nwg >> 3) + (lin >> 3);
  const int my = swz >> 3;                        // 0..63
  const int half = my >> 5;
  const long m0 = (long)(my & 31) * 128;
  const long n0 = (long)(swz & 7) * 128;
  const long k0 = (long)half * 2048;
  short* const Cb = half ? p1 : p0;

  const int rloc = lane >> 3;
  const int csrc = (lane & 7) ^ rloc;
  const short* Ag = A + (m0 + wave * 8 + rloc) * K + csrc * 8 + k0;
  const short* Bg = Bt + (n0 + wave * 8 + rloc) * K + csrc * 8 + k0;
  const int wbase = wave * 512;

  f32x4 acc[4][2] = {};

#define STAGESK(buf, kt)                                                      \
  do {                                                                        \
    gload16(As + (buf) * 8192 + wbase, Ag + (kt));                            \
    gload16(As + (buf) * 8192 + 4096 + wbase, Ag + (long)64 * K + (kt));      \
    gload16(Bs + (buf) * 8192 + wbase, Bg + (kt));                            \
    gload16(Bs + (buf) * 8192 + 4096 + wbase, Bg + (long)64 * K + (kt));      \
  } while (0)

  STAGESK(0, 0);
  STAGESK(1, 64);
  asm volatile("s_waitcnt vmcnt(4)" ::: "memory");
  __builtin_amdgcn_sched_barrier(0);
  __builtin_amdgcn_s_barrier();
  __builtin_amdgcn_sched_barrier(0);

  const int cA = l15 & 7;
  for (int t = 0; t < NT; ++t) {
    const char* Ab = (const char*)(As + (t & 1) * 8192);
    const char* Bb = (const char*)(Bs + (t & 1) * 8192);
#pragma unroll
    for (int kk = 0; kk < 2; ++kk) {
      bf16x8 af[4], bk[2];
#pragma unroll
      for (int mi = 0; mi < 4; ++mi)
        af[mi] = *(const bf16x8*)(Ab + (wm * 64 + mi * 16 + l15) * 128 + 16 * ((kk * 4 + lg) ^ cA));
#pragma unroll
      for (int ni = 0; ni < 2; ++ni)
        bk[ni] = *(const bf16x8*)(Bb + (wn * 32 + ni * 16 + l15) * 128 + 16 * ((kk * 4 + lg) ^ cA));
      __builtin_amdgcn_s_setprio(1);
#pragma unroll
      for (int mi = 0; mi < 4; ++mi)
#pragma unroll
        for (int ni = 0; ni < 2; ++ni)
          acc[mi][ni] = __builtin_amdgcn_mfma_f32_16x16x32_bf16(af[mi], bk[ni], acc[mi][ni], 0, 0, 0);
      __builtin_amdgcn_s_setprio(0);
    }
    if (t == NT - 1) break;
    __builtin_amdgcn_s_barrier();
    __builtin_amdgcn_sched_barrier(0);
    if (t + 2 < NT) {
      STAGESK(t & 1, (long)(t + 2) * 64);
      asm volatile("s_waitcnt vmcnt(4)" ::: "memory");
    } else {
      asm volatile("s_waitcnt vmcnt(0)" ::: "memory");
    }
    __builtin_amdgcn_sched_barrier(0);
    __builtin_amdgcn_s_barrier();
    __builtin_amdgcn_sched_barrier(0);
  }
#undef STAGESK

#pragma unroll
  for (int mi = 0; mi < 4; ++mi) {
#pragma unroll
    for (int ni = 0; ni < 2; ++ni) {
      const long col = n0 + wn * 32 + ni * 16 + l15;
#pragma unroll
      for (int r = 0; r < 4; ++r) {
        const long row = m0 + wm * 64 + mi * 16 + lg * 4 + r;
        Cb[row * N + col] = f2b(acc[mi][ni][r]);
      }
    }
  }
}

// out = p0 + p1 + bias + resid   (fp32 out)
__global__ __launch_bounds__(256)
void reduce_ffn2(const short* __restrict__ p0, const short* __restrict__ p1,
                 const float* __restrict__ bias, const float* __restrict__ resid,
                 float* __restrict__ outp)
{
  const long row = blockIdx.x;
  const int t = threadIdx.x;
  const long base = row * 1024 + t * 4;
  const short4 a = *(const short4*)(p0 + base);
  const short4 b = *(const short4*)(p1 + base);
  const float4 rv = *(const float4*)(resid + base);
  const float4 bv = ((const float4*)bias)[t];
  float4 o;
  o.x = b2f(a.x) + b2f(b.x) + bv.x + rv.x;
  o.y = b2f(a.y) + b2f(b.y) + bv.y + rv.y;
  o.z = b2f(a.z) + b2f(b.z) + bv.z + rv.z;
  o.w = b2f(a.w) + b2f(b.w) + bv.w + rv.w;
  *(float4*)(outp + base) = o;
}

// ---------------- GEMM 256x256, 8-wave, phase-interleaved ----------------
__device__ __forceinline__ void stage256(short* AsB, short* BsB,
                                         const short* Ag, const short* Bg,
                                         long kt, int K, int ldsoff)
{
#pragma unroll
  for (int p = 0; p < 4; ++p)
    gload16(AsB + p * 4096 + ldsoff, Ag + (long)p * 64 * K + kt);
#pragma unroll
  for (int p = 0; p < 4; ++p)
    gload16(BsB + p * 4096 + ldsoff, Bg + (long)p * 64 * K + kt);
}

template<int EPI>
__global__ __launch_bounds__(512, 2)
void gemm256(const short* __restrict__ A, const short* __restrict__ Bt,
             int N, int K, int NT,
             short* __restrict__ Cb, const float* __restrict__ bias)
{
  __shared__ __align__(16) short As[2 * 16384];
  __shared__ __align__(16) short Bs[2 * 16384];
  const int tid = threadIdx.x;
  const int lane = tid & 63;
  const int wave = tid >> 6;
  const int wm = wave >> 2;
  const int wn = wave & 3;
  const int l15 = lane & 15, lg = lane >> 4;

  const int nwg = gridDim.x * gridDim.y;
  const int lin = blockIdx.y * gridDim.x + blockIdx.x;
  const int swz = (lin & 7) * (nwg >> 3) + (lin >> 3);
  const long m0 = (long)(swz / gridDim.x) * 256;
  const long n0 = (long)(swz % gridDim.x) * 256;

  const int trow = tid >> 3;
  const int csrc = (tid & 7) ^ (trow & 7);
  const short* Ag = A + (m0 + trow) * K + csrc * 8;
  const short* Bg = Bt + (n0 + trow) * K + csrc * 8;
  const int ldsoff = wave * 512;

  f32x4 acc[8][4] = {};

  stage256(As, Bs, Ag, Bg, 0, K, ldsoff);
  asm volatile("s_waitcnt vmcnt(0)" ::: "memory");
  __builtin_amdgcn_sched_barrier(0);
  __builtin_amdgcn_s_barrier();
  __builtin_amdgcn_sched_barrier(0);

  const int cA = l15 & 7;
  for (int t = 0; t < NT; ++t) {
    const char* Ab = (const char*)(As + (t & 1) * 16384);
    const char* Bb = (const char*)(Bs + (t & 1) * 16384);
    short* Asn = As + ((t + 1) & 1) * 16384;
    short* Bsn = Bs + ((t + 1) & 1) * 16384;
    const bool more = (t + 1 < NT);
    const long ktn = (long)(t + 1) * 64;
    bf16x8 bk[4];
#pragma unroll
    for (int ph = 0; ph < 4; ++ph) {
      const int kk = ph >> 1;
      const int mh = (ph & 1) * 4;
      bf16x8 af[4];
#pragma unroll
      for (int mi = 0; mi < 4; ++mi)
        af[mi] = *(const bf16x8*)(Ab + (wm * 128 + (mh + mi) * 16 + l15) * 128 + 16 * ((kk * 4 + lg) ^ cA));
      if ((ph & 1) == 0) {
#pragma unroll
        for (int ni = 0; ni < 4; ++ni)
          bk[ni] = *(const bf16x8*)(Bb + (wn * 64 + ni * 16 + l15) * 128 + 16 * ((kk * 4 + lg) ^ cA));
      }
      if (more && ph == 0) {
#pragma unroll
        for (int p = 0; p < 4; ++p)
          gload16(Asn + p * 4096 + ldsoff, Ag + (long)p * 64 * K + ktn);
      }
      if (more && ph == 1) {
#pragma unroll
        for (int p = 0; p < 4; ++p)
          gload16(Bsn + p * 4096 + ldsoff, Bg + (long)p * 64 * K + ktn);
      }
      __builtin_amdgcn_s_barrier();
      asm volatile("s_waitcnt lgkmcnt(0)" ::: "memory");
      __builtin_amdgcn_sched_barrier(0);
      __builtin_amdgcn_s_setprio(1);
#pragma unroll
      for (int mi = 0; mi < 4; ++mi)
#pragma unroll
        for (int ni = 0; ni < 4; ++ni)
          acc[mh + mi][ni] = __builtin_amdgcn_mfma_f32_16x16x32_bf16(af[mi], bk[ni], acc[mh + mi][ni], 0, 0, 0);
      __builtin_amdgcn_s_setprio(0);
      if (ph == 3 && more) {
        asm volatile("s_waitcnt vmcnt(0)" ::: "memory");
        __builtin_amdgcn_sched_barrier(0);
      }
      __builtin_amdgcn_s_barrier();
      __builtin_amdgcn_sched_barrier(0);
    }
  }

#pragma unroll
  for (int mi = 0; mi < 8; ++mi) {
#pragma unroll
    for (int ni = 0; ni < 4; ++ni) {
      const long col = n0 + wn * 64 + ni * 16 + l15;
      const float bb = (EPI == 2) ? bias[col] : 0.f;
#pragma unroll
      for (int r = 0; r < 4; ++r) {
        const long row = m0 + wm * 128 + mi * 16 + lg * 4 + r;
        float v = acc[mi][ni][r];
        if (EPI == 2) { v += bb; v = v > 0.f ? v : 0.f; }
        Cb[row * N + col] = f2b(v);
      }
    }
  }
}

// ---------------- flash attention v6: single-slot wave-private ring ----------
__device__ __forceinline__ void stage_k32(short* lds, const short* gRowBase)
{
  const int lane = threadIdx.x & 63;
  const int rloc = lane >> 3;
  const int cs = (lane & 7) ^ rloc;
#pragma unroll
  for (int p = 0; p < 4; ++p)
    gload16(lds + p * 512, gRowBase + (long)(p * 8 + rloc) * 3072 + cs * 8);
}
__device__ __forceinline__ void stage_v32(short* lds, const short* vHeadBase, int t0)
{
  const int lane = threadIdx.x & 63;
  const int rloc = lane >> 3;
  const int cs = (lane & 7) ^ rloc;
#pragma unroll
  for (int p = 0; p < 4; ++p) {
    const int row = p * 8 + rloc;
    const int d = row + ((cs & 4) << 3);
    gload16(lds + p * 512, vHeadBase + (long)d * 4096 + t0 + (cs & 3) * 8);
  }
}

__global__ __launch_bounds__(256)
void attn_fwd6(const short* __restrict__ qkv, const short* __restrict__ Vt,
               short* __restrict__ outp)
{
  __shared__ __align__(16) short POOL[4 * 4096];  // 32KB: per-wave 1 slot (K|V)
  __shared__ float lAll[64];
  short* const OB = POOL;                         // aliased merge scratch

  const int tid = threadIdx.x;
  const int lane = tid & 63;
  const int wave = tid >> 6;
  const int wq = wave & 1;
  const int ks = wave >> 1;
  const int l31 = lane & 31;
  const int h = lane >> 5;
  const int rs = l31 & 7;

  const int id = blockIdx.x;
  const int head = ((id & 7) << 1) | (id >> 8);
  const int bx = (id >> 3) & 31;

  const short* Qg = qkv + head * 64;
  const short* Kg = qkv + 1024 + head * 64;
  const short* Vg = Vt + (long)head * 262144;

  short* Kw = POOL + wave * 4096;

  bf16x8 onesf;
#pragma unroll
  for (int j = 0; j < 8; ++j) onesf[j] = (short)0x3F80;

  for (int ph = 0; ph < 2; ++ph) {
    const int qsuper = ph ? (63 - bx) : bx;
    const int q0 = qsuper * 64 + wq * 32;
    const int q = q0 + l31;
    const int nt = qsuper + 1;

    bf16x8 qf[4];
#pragma unroll
    for (int d = 0; d < 4; ++d) {
      bf16x8 tq = *(const bf16x8*)(Qg + (long)q * 3072 + d * 16 + h * 8);
#pragma unroll
      for (int j = 0; j < 8; ++j) tq[j] = f2b(b2f(tq[j]) * (0.03125f * 1.44269504f));
      qf[d] = tq;
    }

    f32x16 o0 = {}, o1 = {}, lacc = {};

    stage_k32(Kw, Kg + (long)(ks * 32) * 3072);
    stage_v32(Kw + 2048, Vg, ks * 32);

    for (int t = 0; t < nt; ++t) {
      asm volatile("s_waitcnt vmcnt(0)" ::: "memory");
      __builtin_amdgcn_sched_barrier(0);
      const char* Kb = (const char*)Kw;
      const char* Vb = Kb + 4096;
      const bf16x8 kf0 = *(const bf16x8*)(Kb + l31 * 128 + 16 * ((0 + h) ^ rs));
      const bf16x8 kf1 = *(const bf16x8*)(Kb + l31 * 128 + 16 * ((2 + h) ^ rs));
      const bf16x8 kf2 = *(const bf16x8*)(Kb + l31 * 128 + 16 * ((4 + h) ^ rs));
      const bf16x8 kf3 = *(const bf16x8*)(Kb + l31 * 128 + 16 * ((6 + h) ^ rs));
      const bf16x8 vf00 = *(const bf16x8*)(Vb + l31 * 128 + 16 * ((0 + h) ^ rs));
      const bf16x8 vf01 = *(const bf16x8*)(Vb + l31 * 128 + 16 * ((2 + h) ^ rs));
      const bf16x8 vf10 = *(const bf16x8*)(Vb + l31 * 128 + 16 * ((4 + h) ^ rs));
      const bf16x8 vf11 = *(const bf16x8*)(Vb + l31 * 128 + 16 * ((6 + h) ^ rs));
      asm volatile("s_waitcnt lgkmcnt(0)" ::: "memory");
      __builtin_amdgcn_sched_barrier(0);
      if (t + 1 < nt) {
        stage_k32(Kw, Kg + (long)((t + 1) * 64 + ks * 32) * 3072);
        stage_v32(Kw + 2048, Vg, (t + 1) * 64 + ks * 32);
      }
      f32x16 s = {};
      __builtin_amdgcn_s_setprio(1);
      s = __builtin_amdgcn_mfma_f32_32x32x16_bf16(kf0, qf[0], s, 0, 0, 0);
      s = __builtin_amdgcn_mfma_f32_32x32x16_bf16(kf1, qf[1], s, 0, 0, 0);
      s = __builtin_amdgcn_mfma_f32_32x32x16_bf16(kf2, qf[2], s, 0, 0, 0);
      s = __builtin_amdgcn_mfma_f32_32x32x16_bf16(kf3, qf[3], s, 0, 0, 0);
      __builtin_amdgcn_s_setprio(0);
      if (t == qsuper) {
        const int kb0 = t * 64 + ks * 32 + 4 * h;
#pragma unroll
        for (int r = 0; r < 16; ++r) {
          const int k0 = kb0 + (r & 3) + 8 * (r >> 2);
          if (k0 > q) s[r] = -INFINITY;
        }
      }
#pragma unroll
      for (int r = 0; r < 16; ++r) s[r] = exp2x(s[r]);
      unsigned P0 = cvtpk(s[0], s[1]),   P1 = cvtpk(s[2], s[3]);
      unsigned P2 = cvtpk(s[4], s[5]),   P3 = cvtpk(s[6], s[7]);
      unsigned P4 = cvtpk(s[8], s[9]),   P5 = cvtpk(s[10], s[11]);
      unsigned P6 = cvtpk(s[12], s[13]), P7 = cvtpk(s[14], s[15]);
      plswap(P0, P2); plswap(P1, P3); plswap(P4, P6); plswap(P5, P7);
      u32x4 f0, f1;
      f0[0] = P0; f0[1] = P1; f0[2] = P2; f0[3] = P3;
      f1[0] = P4; f1[1] = P5; f1[2] = P6; f1[3] = P7;
      const bf16x8 pa0 = __builtin_bit_cast(bf16x8, f0);
      const bf16x8 pa1 = __builtin_bit_cast(bf16x8, f1);
      __builtin_amdgcn_s_setprio(1);
      o0 = __builtin_amdgcn_mfma_f32_32x32x16_bf16(pa0, vf00, o0, 0, 0, 0);
      o0 = __builtin_amdgcn_mfma_f32_32x32x16_bf16(pa1, vf01, o0, 0, 0, 0);
      o1 = __builtin_amdgcn_mfma_f32_32x32x16_bf16(pa0, vf10, o1, 0, 0, 0);
      o1 = __builtin_amdgcn_mfma_f32_32x32x16_bf16(pa1, vf11, o1, 0, 0, 0);
      lacc = __builtin_amdgcn_mfma_f32_32x32x16_bf16(pa0, onesf, lacc, 0, 0, 0);
      lacc = __builtin_amdgcn_mfma_f32_32x32x16_bf16(pa1, onesf, lacc, 0, 0, 0);
      __builtin_amdgcn_s_setprio(0);
    }

    __syncthreads();
    if (ks == 1) {
#pragma unroll
      for (int r = 0; r < 16; ++r) {
        const int qq = wq * 32 + (r & 3) + 8 * (r >> 2) + 4 * h;
        OB[qq * 64 + l31] = f2b(o0[r]);
        OB[qq * 64 + 32 + l31] = f2b(o1[r]);
      }
      if (l31 == 0) {
#pragma unroll
        for (int r = 0; r < 16; ++r) {
          const int qq = wq * 32 + (r & 3) + 8 * (r >> 2) + 4 * h;
          lAll[qq] = lacc[r];
        }
      }
    }
    __syncthreads();
    if (ks == 0) {
#pragma unroll
      for (int r = 0; r < 16; ++r) {
        const int qq = wq * 32 + (r & 3) + 8 * (r >> 2) + 4 * h;
        const float inv = 1.f / (lacc[r] + lAll[qq]);
        const long qr = (long)qsuper * 64 + qq;
        const float v0 = o0[r] + b2f(OB[qq * 64 + l31]);
        const float v1 = o1[r] + b2f(OB[qq * 64 + 32 + l31]);
        outp[qr * 1024 + head * 64 + l31] = f2b(v0 * inv);
        outp[qr * 1024 + head * 64 + 32 + l31] = f2b(v1 * inv);
      }
    }
    __syncthreads();
  }
}

// ---------------- launcher ----------------
extern "C" void kernel_launch(void* const* d_in, const int* in_sizes, int n_in,
                              void* d_out, int out_size, void* d_ws, size_t ws_size,
                              hipStream_t stream)
{
  (void)in_sizes; (void)n_in; (void)out_size; (void)ws_size;
  const float* x   = (const float*)d_in[0];
  const float* Wq  = (const float*)d_in[1];
  const float* Wk  = (const float*)d_in[2];
  const float* Wv  = (const float*)d_in[3];
  const float* Wp  = (const float*)d_in[4];
  const float* bp  = (const float*)d_in[5];
  const float* W1  = (const float*)d_in[6];
  const float* b1  = (const float*)d_in[7];
  const float* W2  = (const float*)d_in[8];
  const float* b2  = (const float*)d_in[9];
  const float* g1  = (const float*)d_in[10];
  const float* be1 = (const float*)d_in[11];
  const float* g2  = (const float*)d_in[12];
  const float* be2 = (const float*)d_in[13];
  float* out = (float*)d_out;

  char* ws = (char*)d_ws;
  const size_t MB = 1ull << 20;
  short* WqkvT = (short*)(ws + 0 * MB);    // 6MB (dead after QKV gemm)
  short* WpT   = (short*)(ws + 6 * MB);    // 2MB (dead after proj)
  short* W1T   = (short*)(ws + 8 * MB);    // 8MB (dead after FFN1)
  short* W2T   = (short*)(ws + 16 * MB);   // 8MB (live through FFN2)
  short* hbuf  = (short*)(ws + 24 * MB);   // 8MB (h, then h2; dead after FFN1)
  short* qkvb  = (short*)(ws + 32 * MB);   // qkv 24MB; later ff1 spans 32-64MB (live in FFN2)
  short* attnb = (short*)(ws + 56 * MB);   // 8MB (clobbered by ff1 later - attn out consumed by proj first)
  float* x1    = (float*)(ws + 64 * MB);   // 16MB (live through reduce)
  short* Vtb   = (short*)(ws + 64 * MB);   // 8MB (dead before x1 write)
  // FFN2 split-K partials (regions dead by FFN2 time):
  short* p0buf = (short*)(ws + 0 * MB);    // 8MB over WqkvT/WpT
  short* p1buf = (short*)(ws + 8 * MB);    // 8MB over W1T

  prep_all<<<16384, 256, 0, stream>>>(Wq, Wk, Wv, Wp, W1, W2, x, g1, be1,
                                      WqkvT, WpT, W1T, W2T, hbuf);
  gemm256<0><<<dim3(12, 16), 512, 0, stream>>>(hbuf, WqkvT, 3072, 1024, 16,
                                               qkvb, nullptr);
  vtrans<<<dim3(128, 32), dim3(32, 8), 0, stream>>>(qkvb, Vtb);
  attn_fwd6<<<512, 256, 0, stream>>>(qkvb, Vtb, attnb);
  gemm128<1><<<dim3(8, 32), 512, 0, stream>>>(attnb, WpT, 1024, 1024, 16,
                                              nullptr, x1, bp, x);
  layernorm_bf16<<<4096, 256, 0, stream>>>(x1, g2, be2, hbuf);
  gemm256<2><<<dim3(16, 16), 512, 0, stream>>>(hbuf, W1T, 4096, 1024, 16,
                                               qkvb, b1);
  // FFN2: split-K2 (512 blocks, 2/CU) -> bf16 partials -> reduce
  gemm128sk<<<dim3(8, 64), 512, 0, stream>>>(qkvb, W2T, 1024, 4096, 32,
                                             p0buf, p1buf);
  reduce_ffn2<<<4096, 256, 0, stream>>>(p0buf, p1buf, b2, x1, out);
}

// Round 16
// 229.571 us; speedup vs baseline: 1.1101x; 1.0084x over previous
//
#include <hip/hip_runtime.h>
#include <cstdint>

typedef __attribute__((ext_vector_type(8))) short bf16x8;
typedef __attribute__((ext_vector_type(4))) float f32x4;
typedef __attribute__((ext_vector_type(16))) float f32x16;
typedef __attribute__((ext_vector_type(4))) unsigned int u32x4;

__device__ __forceinline__ short f2b(float f) {
  unsigned u = __builtin_bit_cast(unsigned, f);
  unsigned r = (u + 0x7fffu + ((u >> 16) & 1u)) >> 16;
  return (short)(unsigned short)r;
}
__device__ __forceinline__ float b2f(short s) {
  unsigned u = ((unsigned)(unsigned short)s) << 16;
  return __builtin_bit_cast(float, u);
}

__device__ __forceinline__ void gload16(void* lds_dst, const void* gsrc) {
  __builtin_amdgcn_global_load_lds(
      (const __attribute__((address_space(1))) void*)gsrc,
      (__attribute__((address_space(3))) void*)lds_dst, 16, 0, 0);
}

__device__ __forceinline__ unsigned cvtpk(float a, float b) {
  unsigned r;
  asm("v_cvt_pk_bf16_f32 %0, %1, %2" : "=v"(r) : "v"(a), "v"(b));
  return r;
}
__device__ __forceinline__ unsigned shflx32(unsigned v) {
  return (unsigned)__shfl_xor((int)v, 32);
}
__device__ __forceinline__ float exp2x(float x) {
  float r;
  asm("v_exp_f32 %0, %1" : "=v"(r) : "v"(x));
  return r;
}

// cross-half swap
__device__ __forceinline__ void plswap(unsigned &a, unsigned &b) {
#if __has_builtin(__builtin_amdgcn_permlane32_swap)
  auto r = __builtin_amdgcn_permlane32_swap((int)a, (int)b, false, false);
  a = (unsigned)r[0];
  b = (unsigned)r[1];
#else
  const bool lo = ((threadIdx.x & 63) < 32);
  unsigned ax = shflx32(a), bx = shflx32(b);
  unsigned na = lo ? a : bx;
  unsigned nb = lo ? ax : b;
  a = na; b = nb;
#endif
}

// ---------------- fused prep: qkv_pack + Wp/W1/W2 transpose + LN1 ----------------
__global__ __launch_bounds__(256)
void prep_all(const float* __restrict__ Wq, const float* __restrict__ Wk,
              const float* __restrict__ Wv, const float* __restrict__ Wp,
              const float* __restrict__ W1, const float* __restrict__ W2,
              const float* __restrict__ x, const float* __restrict__ g1,
              const float* __restrict__ be1,
              short* __restrict__ WqkvT, short* __restrict__ WpT,
              short* __restrict__ W1T, short* __restrict__ W2T,
              short* __restrict__ hbuf)
{
  const int id = blockIdx.x;
  if (id < 12288) {
    __shared__ float tl[32][33];
    const int tx = threadIdx.x & 31;
    const int ty = threadIdx.x >> 5;
    if (id < 3072) {
      const int which = id >> 10;
      const int rem = id & 1023;
      const int head = rem >> 6;
      const int tile = rem & 63;
      const int tc = tile >> 1, td = tile & 1;
      const float* src = (which == 0 ? Wq : which == 1 ? Wk : Wv) + (long)head * 65536;
#pragma unroll
      for (int i2 = 0; i2 < 4; ++i2) {
        int i = ty + i2 * 8;
        tl[i][tx] = src[(long)(tc * 32 + i) * 64 + td * 32 + tx];
      }
      __syncthreads();
      const long base = (long)which * 1024 + head * 64 + td * 32;
#pragma unroll
      for (int i2 = 0; i2 < 4; ++i2) {
        int i = ty + i2 * 8;
        WqkvT[(base + i) * 1024 + tc * 32 + tx] = f2b(tl[tx][i]);
      }
    } else {
      const float* src;
      short* dst;
      int rows, cols, bx, by;
      if (id < 4096) {
        src = Wp; dst = WpT; rows = 1024; cols = 1024;
        const int k = id - 3072; bx = k & 31; by = k >> 5;
      } else if (id < 8192) {
        src = W1; dst = W1T; rows = 1024; cols = 4096;
        const int k = id - 4096; bx = k & 127; by = k >> 7;
      } else {
        src = W2; dst = W2T; rows = 4096; cols = 1024;
        const int k = id - 8192; bx = k & 31; by = k >> 5;
      }
#pragma unroll
      for (int i2 = 0; i2 < 4; ++i2) {
        int i = ty + i2 * 8;
        tl[i][tx] = src[(long)(by * 32 + i) * cols + bx * 32 + tx];
      }
      __syncthreads();
#pragma unroll
      for (int i2 = 0; i2 < 4; ++i2) {
        int i = ty + i2 * 8;
        dst[(long)(bx * 32 + i) * rows + by * 32 + tx] = f2b(tl[tx][i]);
      }
    }
  } else {
    const int row = id - 12288;
    const int t = threadIdx.x;
    const float4 v = ((const float4*)(x + (long)row * 1024))[t];
    float s = v.x + v.y + v.z + v.w;
    float ss = v.x * v.x + v.y * v.y + v.z * v.z + v.w * v.w;
#pragma unroll
    for (int off = 1; off < 64; off <<= 1) {
      s += __shfl_xor(s, off);
      ss += __shfl_xor(ss, off);
    }
    __shared__ float red[8];
    const int wave = t >> 6, lane = t & 63;
    if (lane == 0) { red[wave] = s; red[4 + wave] = ss; }
    __syncthreads();
    s = red[0] + red[1] + red[2] + red[3];
    ss = red[4] + red[5] + red[6] + red[7];
    const float mu = s * (1.f / 1024.f);
    const float rstd = rsqrtf(ss * (1.f / 1024.f) - mu * mu + 1e-5f);
    const float4 gv = ((const float4*)g1)[t];
    const float4 bv = ((const float4*)be1)[t];
    short4 ov;
    ov.x = f2b((v.x - mu) * rstd * gv.x + bv.x);
    ov.y = f2b((v.y - mu) * rstd * gv.y + bv.y);
    ov.z = f2b((v.z - mu) * rstd * gv.z + bv.z);
    ov.w = f2b((v.w - mu) * rstd * gv.w + bv.w);
    *(short4*)(hbuf + (long)row * 1024 + t * 4) = ov;
  }
}

// V part of qkv [4096][3072] -> Vt [16][64][4096] bf16
__global__ void vtrans(const short* __restrict__ qkv, short* __restrict__ Vt)
{
  __shared__ short tl[32][33];
  const int t0 = blockIdx.x * 32;
  const int c0 = blockIdx.y * 32;
  const int head = c0 >> 6, d0 = c0 & 63;
  const int tx = threadIdx.x;
#pragma unroll
  for (int i2 = 0; i2 < 4; ++i2) {
    int i = threadIdx.y + i2 * 8;
    tl[i][tx] = qkv[(long)(t0 + i) * 3072 + 2048 + c0 + tx];
  }
  __syncthreads();
#pragma unroll
  for (int i2 = 0; i2 < 4; ++i2) {
    int i = threadIdx.y + i2 * 8;
    Vt[(long)head * 262144 + (long)(d0 + i) * 4096 + t0 + tx] = tl[tx][i];
  }
}

// ---------------- GEMM 128x128 split-K2: bf16 partials ----------------
// grid (8, 64): y = mtile(0..31) + 32*half; k-slice = half*(K/2), NT=(K/2)/64.
__global__ __launch_bounds__(512, 2)
void gemm128sk(const short* __restrict__ A, const short* __restrict__ Bt,
               int N, int K, int NT,
               short* __restrict__ p0, short* __restrict__ p1)
{
  __shared__ __align__(16) short As[2 * 8192];
  __shared__ __align__(16) short Bs[2 * 8192];
  const int tid = threadIdx.x;
  const int lane = tid & 63;
  const int wave = tid >> 6;
  const int wm = wave >> 2;
  const int wn = wave & 3;
  const int l15 = lane & 15, lg = lane >> 4;

  const int nwg = gridDim.x * gridDim.y;          // 512
  const int lin = blockIdx.y * gridDim.x + blockIdx.x;
  const int swz = (lin & 7) * (nwg >> 3) + (lin >> 3);
  const int my = swz >> 3;                        // 0..63
  const int half = my >> 5;
  const long m0 = (long)(my & 31) * 128;
  const long n0 = (long)(swz & 7) * 128;
  const long k0 = (long)half * (K >> 1);
  short* const Cb = half ? p1 : p0;

  const int rloc = lane >> 3;
  const int csrc = (lane & 7) ^ rloc;
  const short* Ag = A + (m0 + wave * 8 + rloc) * K + csrc * 8 + k0;
  const short* Bg = Bt + (n0 + wave * 8 + rloc) * K + csrc * 8 + k0;
  const int wbase = wave * 512;

  f32x4 acc[4][2] = {};

#define STAGESK(buf, kt)                                                      \
  do {                                                                        \
    gload16(As + (buf) * 8192 + wbase, Ag + (kt));                            \
    gload16(As + (buf) * 8192 + 4096 + wbase, Ag + (long)64 * K + (kt));      \
    gload16(Bs + (buf) * 8192 + wbase, Bg + (kt));                            \
    gload16(Bs + (buf) * 8192 + 4096 + wbase, Bg + (long)64 * K + (kt));      \
  } while (0)

  STAGESK(0, 0);
  STAGESK(1, 64);
  asm volatile("s_waitcnt vmcnt(4)" ::: "memory");
  __builtin_amdgcn_sched_barrier(0);
  __builtin_amdgcn_s_barrier();
  __builtin_amdgcn_sched_barrier(0);

  const int cA = l15 & 7;
  for (int t = 0; t < NT; ++t) {
    const char* Ab = (const char*)(As + (t & 1) * 8192);
    const char* Bb = (const char*)(Bs + (t & 1) * 8192);
#pragma unroll
    for (int kk = 0; kk < 2; ++kk) {
      bf16x8 af[4], bk[2];
#pragma unroll
      for (int mi = 0; mi < 4; ++mi)
        af[mi] = *(const bf16x8*)(Ab + (wm * 64 + mi * 16 + l15) * 128 + 16 * ((kk * 4 + lg) ^ cA));
#pragma unroll
      for (int ni = 0; ni < 2; ++ni)
        bk[ni] = *(const bf16x8*)(Bb + (wn * 32 + ni * 16 + l15) * 128 + 16 * ((kk * 4 + lg) ^ cA));
      __builtin_amdgcn_s_setprio(1);
#pragma unroll
      for (int mi = 0; mi < 4; ++mi)
#pragma unroll
        for (int ni = 0; ni < 2; ++ni)
          acc[mi][ni] = __builtin_amdgcn_mfma_f32_16x16x32_bf16(af[mi], bk[ni], acc[mi][ni], 0, 0, 0);
      __builtin_amdgcn_s_setprio(0);
    }
    if (t == NT - 1) break;
    __builtin_amdgcn_s_barrier();
    __builtin_amdgcn_sched_barrier(0);
    if (t + 2 < NT) {
      STAGESK(t & 1, (long)(t + 2) * 64);
      asm volatile("s_waitcnt vmcnt(4)" ::: "memory");
    } else {
      asm volatile("s_waitcnt vmcnt(0)" ::: "memory");
    }
    __builtin_amdgcn_sched_barrier(0);
    __builtin_amdgcn_s_barrier();
    __builtin_amdgcn_sched_barrier(0);
  }
#undef STAGESK

#pragma unroll
  for (int mi = 0; mi < 4; ++mi) {
#pragma unroll
    for (int ni = 0; ni < 2; ++ni) {
      const long col = n0 + wn * 32 + ni * 16 + l15;
#pragma unroll
      for (int r = 0; r < 4; ++r) {
        const long row = m0 + wm * 64 + mi * 16 + lg * 4 + r;
        Cb[row * N + col] = f2b(acc[mi][ni][r]);
      }
    }
  }
}

// out = p0 + p1 + bias + resid   (fp32 out) — FFN2 tail
__global__ __launch_bounds__(256)
void reduce_ffn2(const short* __restrict__ p0, const short* __restrict__ p1,
                 const float* __restrict__ bias, const float* __restrict__ resid,
                 float* __restrict__ outp)
{
  const long row = blockIdx.x;
  const int t = threadIdx.x;
  const long base = row * 1024 + t * 4;
  const short4 a = *(const short4*)(p0 + base);
  const short4 b = *(const short4*)(p1 + base);
  const float4 rv = *(const float4*)(resid + base);
  const float4 bv = ((const float4*)bias)[t];
  float4 o;
  o.x = b2f(a.x) + b2f(b.x) + bv.x + rv.x;
  o.y = b2f(a.y) + b2f(b.y) + bv.y + rv.y;
  o.z = b2f(a.z) + b2f(b.z) + bv.z + rv.z;
  o.w = b2f(a.w) + b2f(b.w) + bv.w + rv.w;
  *(float4*)(outp + base) = o;
}

// proj tail fused with LN2: x1 = p0+p1+bp+x ; h2 = LN(x1)*g2+be2
__global__ __launch_bounds__(256)
void reduce_ln2(const short* __restrict__ p0, const short* __restrict__ p1,
                const float* __restrict__ bp, const float* __restrict__ xres,
                const float* __restrict__ g2, const float* __restrict__ be2,
                float* __restrict__ x1, short* __restrict__ hbuf)
{
  const long row = blockIdx.x;
  const int t = threadIdx.x;
  const long base = row * 1024 + t * 4;
  const short4 a = *(const short4*)(p0 + base);
  const short4 b = *(const short4*)(p1 + base);
  const float4 rv = *(const float4*)(xres + base);
  const float4 bpv = ((const float4*)bp)[t];
  float4 v;
  v.x = b2f(a.x) + b2f(b.x) + bpv.x + rv.x;
  v.y = b2f(a.y) + b2f(b.y) + bpv.y + rv.y;
  v.z = b2f(a.z) + b2f(b.z) + bpv.z + rv.z;
  v.w = b2f(a.w) + b2f(b.w) + bpv.w + rv.w;
  *(float4*)(x1 + base) = v;
  float s = v.x + v.y + v.z + v.w;
  float ss = v.x * v.x + v.y * v.y + v.z * v.z + v.w * v.w;
#pragma unroll
  for (int off = 1; off < 64; off <<= 1) {
    s += __shfl_xor(s, off);
    ss += __shfl_xor(ss, off);
  }
  __shared__ float red[8];
  const int wave = t >> 6, lane = t & 63;
  if (lane == 0) { red[wave] = s; red[4 + wave] = ss; }
  __syncthreads();
  s = red[0] + red[1] + red[2] + red[3];
  ss = red[4] + red[5] + red[6] + red[7];
  const float mu = s * (1.f / 1024.f);
  const float rstd = rsqrtf(ss * (1.f / 1024.f) - mu * mu + 1e-5f);
  const float4 gv = ((const float4*)g2)[t];
  const float4 bv = ((const float4*)be2)[t];
  short4 ov;
  ov.x = f2b((v.x - mu) * rstd * gv.x + bv.x);
  ov.y = f2b((v.y - mu) * rstd * gv.y + bv.y);
  ov.z = f2b((v.z - mu) * rstd * gv.z + bv.z);
  ov.w = f2b((v.w - mu) * rstd * gv.w + bv.w);
  *(short4*)(hbuf + base) = ov;
}

// ---------------- GEMM 256x256, 8-wave, phase-interleaved ----------------
__device__ __forceinline__ void stage256(short* AsB, short* BsB,
                                         const short* Ag, const short* Bg,
                                         long kt, int K, int ldsoff)
{
#pragma unroll
  for (int p = 0; p < 4; ++p)
    gload16(AsB + p * 4096 + ldsoff, Ag + (long)p * 64 * K + kt);
#pragma unroll
  for (int p = 0; p < 4; ++p)
    gload16(BsB + p * 4096 + ldsoff, Bg + (long)p * 64 * K + kt);
}

template<int EPI>
__global__ __launch_bounds__(512, 2)
void gemm256(const short* __restrict__ A, const short* __restrict__ Bt,
             int N, int K, int NT,
             short* __restrict__ Cb, const float* __restrict__ bias)
{
  __shared__ __align__(16) short As[2 * 16384];
  __shared__ __align__(16) short Bs[2 * 16384];
  const int tid = threadIdx.x;
  const int lane = tid & 63;
  const int wave = tid >> 6;
  const int wm = wave >> 2;
  const int wn = wave & 3;
  const int l15 = lane & 15, lg = lane >> 4;

  const int nwg = gridDim.x * gridDim.y;
  const int lin = blockIdx.y * gridDim.x + blockIdx.x;
  const int swz = (lin & 7) * (nwg >> 3) + (lin >> 3);
  const long m0 = (long)(swz / gridDim.x) * 256;
  const long n0 = (long)(swz % gridDim.x) * 256;

  const int trow = tid >> 3;
  const int csrc = (tid & 7) ^ (trow & 7);
  const short* Ag = A + (m0 + trow) * K + csrc * 8;
  const short* Bg = Bt + (n0 + trow) * K + csrc * 8;
  const int ldsoff = wave * 512;

  f32x4 acc[8][4] = {};

  stage256(As, Bs, Ag, Bg, 0, K, ldsoff);
  asm volatile("s_waitcnt vmcnt(0)" ::: "memory");
  __builtin_amdgcn_sched_barrier(0);
  __builtin_amdgcn_s_barrier();
  __builtin_amdgcn_sched_barrier(0);

  const int cA = l15 & 7;
  for (int t = 0; t < NT; ++t) {
    const char* Ab = (const char*)(As + (t & 1) * 16384);
    const char* Bb = (const char*)(Bs + (t & 1) * 16384);
    short* Asn = As + ((t + 1) & 1) * 16384;
    short* Bsn = Bs + ((t + 1) & 1) * 16384;
    const bool more = (t + 1 < NT);
    const long ktn = (long)(t + 1) * 64;
    bf16x8 bk[4];
#pragma unroll
    for (int ph = 0; ph < 4; ++ph) {
      const int kk = ph >> 1;
      const int mh = (ph & 1) * 4;
      bf16x8 af[4];
#pragma unroll
      for (int mi = 0; mi < 4; ++mi)
        af[mi] = *(const bf16x8*)(Ab + (wm * 128 + (mh + mi) * 16 + l15) * 128 + 16 * ((kk * 4 + lg) ^ cA));
      if ((ph & 1) == 0) {
#pragma unroll
        for (int ni = 0; ni < 4; ++ni)
          bk[ni] = *(const bf16x8*)(Bb + (wn * 64 + ni * 16 + l15) * 128 + 16 * ((kk * 4 + lg) ^ cA));
      }
      if (more && ph == 0) {
#pragma unroll
        for (int p = 0; p < 4; ++p)
          gload16(Asn + p * 4096 + ldsoff, Ag + (long)p * 64 * K + ktn);
      }
      if (more && ph == 1) {
#pragma unroll
        for (int p = 0; p < 4; ++p)
          gload16(Bsn + p * 4096 + ldsoff, Bg + (long)p * 64 * K + ktn);
      }
      __builtin_amdgcn_s_barrier();
      asm volatile("s_waitcnt lgkmcnt(0)" ::: "memory");
      __builtin_amdgcn_sched_barrier(0);
      __builtin_amdgcn_s_setprio(1);
#pragma unroll
      for (int mi = 0; mi < 4; ++mi)
#pragma unroll
        for (int ni = 0; ni < 4; ++ni)
          acc[mh + mi][ni] = __builtin_amdgcn_mfma_f32_16x16x32_bf16(af[mi], bk[ni], acc[mh + mi][ni], 0, 0, 0);
      __builtin_amdgcn_s_setprio(0);
      if (ph == 3 && more) {
        asm volatile("s_waitcnt vmcnt(0)" ::: "memory");
        __builtin_amdgcn_sched_barrier(0);
      }
      __builtin_amdgcn_s_barrier();
      __builtin_amdgcn_sched_barrier(0);
    }
  }

#pragma unroll
  for (int mi = 0; mi < 8; ++mi) {
#pragma unroll
    for (int ni = 0; ni < 4; ++ni) {
      const long col = n0 + wn * 64 + ni * 16 + l15;
      const float bb = (EPI == 2) ? bias[col] : 0.f;
#pragma unroll
      for (int r = 0; r < 4; ++r) {
        const long row = m0 + wm * 128 + mi * 16 + lg * 4 + r;
        float v = acc[mi][ni][r];
        if (EPI == 2) { v += bb; v = v > 0.f ? v : 0.f; }
        Cb[row * N + col] = f2b(v);
      }
    }
  }
}

// ---------------- flash attention v6: single-slot wave-private ring ----------
__device__ __forceinline__ void stage_k32(short* lds, const short* gRowBase)
{
  const int lane = threadIdx.x & 63;
  const int rloc = lane >> 3;
  const int cs = (lane & 7) ^ rloc;
#pragma unroll
  for (int p = 0; p < 4; ++p)
    gload16(lds + p * 512, gRowBase + (long)(p * 8 + rloc) * 3072 + cs * 8);
}
__device__ __forceinline__ void stage_v32(short* lds, const short* vHeadBase, int t0)
{
  const int lane = threadIdx.x & 63;
  const int rloc = lane >> 3;
  const int cs = (lane & 7) ^ rloc;
#pragma unroll
  for (int p = 0; p < 4; ++p) {
    const int row = p * 8 + rloc;
    const int d = row + ((cs & 4) << 3);
    gload16(lds + p * 512, vHeadBase + (long)d * 4096 + t0 + (cs & 3) * 8);
  }
}

__global__ __launch_bounds__(256)
void attn_fwd6(const short* __restrict__ qkv, const short* __restrict__ Vt,
               short* __restrict__ outp)
{
  __shared__ __align__(16) short POOL[4 * 4096];
  __shared__ float lAll[64];
  short* const OB = POOL;

  const int tid = threadIdx.x;
  const int lane = tid & 63;
  const int wave = tid >> 6;
  const int wq = wave & 1;
  const int ks = wave >> 1;
  const int l31 = lane & 31;
  const int h = lane >> 5;
  const int rs = l31 & 7;

  const int id = blockIdx.x;
  const int head = ((id & 7) << 1) | (id >> 8);
  const int bx = (id >> 3) & 31;

  const short* Qg = qkv + head * 64;
  const short* Kg = qkv + 1024 + head * 64;
  const short* Vg = Vt + (long)head * 262144;

  short* Kw = POOL + wave * 4096;

  bf16x8 onesf;
#pragma unroll
  for (int j = 0; j < 8; ++j) onesf[j] = (short)0x3F80;

  for (int ph = 0; ph < 2; ++ph) {
    const int qsuper = ph ? (63 - bx) : bx;
    const int q0 = qsuper * 64 + wq * 32;
    const int q = q0 + l31;
    const int nt = qsuper + 1;

    bf16x8 qf[4];
#pragma unroll
    for (int d = 0; d < 4; ++d) {
      bf16x8 tq = *(const bf16x8*)(Qg + (long)q * 3072 + d * 16 + h * 8);
#pragma unroll
      for (int j = 0; j < 8; ++j) tq[j] = f2b(b2f(tq[j]) * (0.03125f * 1.44269504f));
      qf[d] = tq;
    }

    f32x16 o0 = {}, o1 = {}, lacc = {};

    stage_k32(Kw, Kg + (long)(ks * 32) * 3072);
    stage_v32(Kw + 2048, Vg, ks * 32);

    for (int t = 0; t < nt; ++t) {
      asm volatile("s_waitcnt vmcnt(0)" ::: "memory");
      __builtin_amdgcn_sched_barrier(0);
      const char* Kb = (const char*)Kw;
      const char* Vb = Kb + 4096;
      const bf16x8 kf0 = *(const bf16x8*)(Kb + l31 * 128 + 16 * ((0 + h) ^ rs));
      const bf16x8 kf1 = *(const bf16x8*)(Kb + l31 * 128 + 16 * ((2 + h) ^ rs));
      const bf16x8 kf2 = *(const bf16x8*)(Kb + l31 * 128 + 16 * ((4 + h) ^ rs));
      const bf16x8 kf3 = *(const bf16x8*)(Kb + l31 * 128 + 16 * ((6 + h) ^ rs));
      const bf16x8 vf00 = *(const bf16x8*)(Vb + l31 * 128 + 16 * ((0 + h) ^ rs));
      const bf16x8 vf01 = *(const bf16x8*)(Vb + l31 * 128 + 16 * ((2 + h) ^ rs));
      const bf16x8 vf10 = *(const bf16x8*)(Vb + l31 * 128 + 16 * ((4 + h) ^ rs));
      const bf16x8 vf11 = *(const bf16x8*)(Vb + l31 * 128 + 16 * ((6 + h) ^ rs));
      asm volatile("s_waitcnt lgkmcnt(0)" ::: "memory");
      __builtin_amdgcn_sched_barrier(0);
      if (t + 1 < nt) {
        stage_k32(Kw, Kg + (long)((t + 1) * 64 + ks * 32) * 3072);
        stage_v32(Kw + 2048, Vg, (t + 1) * 64 + ks * 32);
      }
      f32x16 s = {};
      __builtin_amdgcn_s_setprio(1);
      s = __builtin_amdgcn_mfma_f32_32x32x16_bf16(kf0, qf[0], s, 0, 0, 0);
      s = __builtin_amdgcn_mfma_f32_32x32x16_bf16(kf1, qf[1], s, 0, 0, 0);
      s = __builtin_amdgcn_mfma_f32_32x32x16_bf16(kf2, qf[2], s, 0, 0, 0);
      s = __builtin_amdgcn_mfma_f32_32x32x16_bf16(kf3, qf[3], s, 0, 0, 0);
      __builtin_amdgcn_s_setprio(0);
      if (t == qsuper) {
        const int kb0 = t * 64 + ks * 32 + 4 * h;
#pragma unroll
        for (int r = 0; r < 16; ++r) {
          const int k0 = kb0 + (r & 3) + 8 * (r >> 2);
          if (k0 > q) s[r] = -INFINITY;
        }
      }
#pragma unroll
      for (int r = 0; r < 16; ++r) s[r] = exp2x(s[r]);
      unsigned P0 = cvtpk(s[0], s[1]),   P1 = cvtpk(s[2], s[3]);
      unsigned P2 = cvtpk(s[4], s[5]),   P3 = cvtpk(s[6], s[7]);
      unsigned P4 = cvtpk(s[8], s[9]),   P5 = cvtpk(s[10], s[11]);
      unsigned P6 = cvtpk(s[12], s[13]), P7 = cvtpk(s[14], s[15]);
      plswap(P0, P2); plswap(P1, P3); plswap(P4, P6); plswap(P5, P7);
      u32x4 f0, f1;
      f0[0] = P0; f0[1] = P1; f0[2] = P2; f0[3] = P3;
      f1[0] = P4; f1[1] = P5; f1[2] = P6; f1[3] = P7;
      const bf16x8 pa0 = __builtin_bit_cast(bf16x8, f0);
      const bf16x8 pa1 = __builtin_bit_cast(bf16x8, f1);
      __builtin_amdgcn_s_setprio(1);
      o0 = __builtin_amdgcn_mfma_f32_32x32x16_bf16(pa0, vf00, o0, 0, 0, 0);
      o0 = __builtin_amdgcn_mfma_f32_32x32x16_bf16(pa1, vf01, o0, 0, 0, 0);
      o1 = __builtin_amdgcn_mfma_f32_32x32x16_bf16(pa0, vf10, o1, 0, 0, 0);
      o1 = __builtin_amdgcn_mfma_f32_32x32x16_bf16(pa1, vf11, o1, 0, 0, 0);
      lacc = __builtin_amdgcn_mfma_f32_32x32x16_bf16(pa0, onesf, lacc, 0, 0, 0);
      lacc = __builtin_amdgcn_mfma_f32_32x32x16_bf16(pa1, onesf, lacc, 0, 0, 0);
      __builtin_amdgcn_s_setprio(0);
    }

    __syncthreads();
    if (ks == 1) {
#pragma unroll
      for (int r = 0; r < 16; ++r) {
        const int qq = wq * 32 + (r & 3) + 8 * (r >> 2) + 4 * h;
        OB[qq * 64 + l31] = f2b(o0[r]);
        OB[qq * 64 + 32 + l31] = f2b(o1[r]);
      }
      if (l31 == 0) {
#pragma unroll
        for (int r = 0; r < 16; ++r) {
          const int qq = wq * 32 + (r & 3) + 8 * (r >> 2) + 4 * h;
          lAll[qq] = lacc[r];
        }
      }
    }
    __syncthreads();
    if (ks == 0) {
#pragma unroll
      for (int r = 0; r < 16; ++r) {
        const int qq = wq * 32 + (r & 3) + 8 * (r >> 2) + 4 * h;
        const float inv = 1.f / (lacc[r] + lAll[qq]);
        const long qr = (long)qsuper * 64 + qq;
        const float v0 = o0[r] + b2f(OB[qq * 64 + l31]);
        const float v1 = o1[r] + b2f(OB[qq * 64 + 32 + l31]);
        outp[qr * 1024 + head * 64 + l31] = f2b(v0 * inv);
        outp[qr * 1024 + head * 64 + 32 + l31] = f2b(v1 * inv);
      }
    }
    __syncthreads();
  }
}

// ---------------- launcher ----------------
extern "C" void kernel_launch(void* const* d_in, const int* in_sizes, int n_in,
                              void* d_out, int out_size, void* d_ws, size_t ws_size,
                              hipStream_t stream)
{
  (void)in_sizes; (void)n_in; (void)out_size; (void)ws_size;
  const float* x   = (const float*)d_in[0];
  const float* Wq  = (const float*)d_in[1];
  const float* Wk  = (const float*)d_in[2];
  const float* Wv  = (const float*)d_in[3];
  const float* Wp  = (const float*)d_in[4];
  const float* bp  = (const float*)d_in[5];
  const float* W1  = (const float*)d_in[6];
  const float* b1  = (const float*)d_in[7];
  const float* W2  = (const float*)d_in[8];
  const float* b2  = (const float*)d_in[9];
  const float* g1  = (const float*)d_in[10];
  const float* be1 = (const float*)d_in[11];
  const float* g2  = (const float*)d_in[12];
  const float* be2 = (const float*)d_in[13];
  float* out = (float*)d_out;

  char* ws = (char*)d_ws;
  const size_t MB = 1ull << 20;
  short* WqkvT = (short*)(ws + 0 * MB);    // 6MB (dead after QKV gemm)
  short* WpT   = (short*)(ws + 6 * MB);    // 2MB (dead after proj)
  short* W1T   = (short*)(ws + 8 * MB);    // 8MB (dead after FFN1)
  short* W2T   = (short*)(ws + 16 * MB);   // 8MB (live through FFN2)
  short* hbuf  = (short*)(ws + 24 * MB);   // 8MB (h; h2 after reduce_ln2)
  short* qkvb  = (short*)(ws + 32 * MB);   // qkv 24MB (dead after attn); ff1 spans 32-64MB
  short* attnb = (short*)(ws + 56 * MB);   // 8MB attn out (dead after proj)
  float* x1    = (float*)(ws + 64 * MB);   // 16MB (live through reduce_ffn2)
  short* Vtb   = (short*)(ws + 64 * MB);   // 8MB (dead before x1 write)
  // proj split-K partials: qkvb region (dead after attn, consumed before FFN1)
  short* p0p   = (short*)(ws + 32 * MB);   // 8MB
  short* p1p   = (short*)(ws + 40 * MB);   // 8MB
  // FFN2 split-K partials: weight regions (dead by FFN2 time)
  short* p0buf = (short*)(ws + 0 * MB);    // 8MB over WqkvT/WpT
  short* p1buf = (short*)(ws + 8 * MB);    // 8MB over W1T

  prep_all<<<16384, 256, 0, stream>>>(Wq, Wk, Wv, Wp, W1, W2, x, g1, be1,
                                      WqkvT, WpT, W1T, W2T, hbuf);
  gemm256<0><<<dim3(12, 16), 512, 0, stream>>>(hbuf, WqkvT, 3072, 1024, 16,
                                               qkvb, nullptr);
  vtrans<<<dim3(128, 32), dim3(32, 8), 0, stream>>>(qkvb, Vtb);
  attn_fwd6<<<512, 256, 0, stream>>>(qkvb, Vtb, attnb);
  // proj: split-K2 (512 blocks, 2/CU) -> bf16 partials
  gemm128sk<<<dim3(8, 64), 512, 0, stream>>>(attnb, WpT, 1024, 1024, 8,
                                             p0p, p1p);
  // fused: x1 = p0+p1+bp+x ; h2 = LN2(x1)
  reduce_ln2<<<4096, 256, 0, stream>>>(p0p, p1p, bp, x, g2, be2, x1, hbuf);
  gemm256<2><<<dim3(16, 16), 512, 0, stream>>>(hbuf, W1T, 4096, 1024, 16,
                                               qkvb, b1);
  gemm128sk<<<dim3(8, 64), 512, 0, stream>>>(qkvb, W2T, 1024, 4096, 32,
                                             p0buf, p1buf);
  reduce_ffn2<<<4096, 256, 0, stream>>>(p0buf, p1buf, b2, x1, out);
}